// Round 2
// baseline (3335.882 us; speedup 1.0000x reference)
//
#include <hip/hip_runtime.h>
#include <stdint.h>

#define BB 256
#define SS 64
#define TT 20
#define HH 1024
#define EE 100
#define G3 3072
#define G4 4096
#define KE 1152     // 1024 + 128 (E padded to 128)
#define VV 32000
#define GRIDN 128   // blocks in persistent recurrent kernels (<= 256 CUs)

typedef unsigned short ushort_t;
typedef short bf16x8 __attribute__((ext_vector_type(8)));
typedef float f32x4 __attribute__((ext_vector_type(4)));

#define DEV static __device__ __forceinline__

DEV float bf2f(ushort_t h) {
    union { uint32_t u; float f; } c; c.u = ((uint32_t)h) << 16; return c.f;
}
DEV ushort_t f2bf(float x) {
    union { float f; uint32_t u; } c; c.f = x;
    uint32_t r = (c.u + 0x7fffu + ((c.u >> 16) & 1u)) >> 16;
    return (ushort_t)r;
}
DEV float sigm(float x) { return 1.f / (1.f + expf(-x)); }

DEV void storeC(float* p, float v) { *p = v; }
DEV void storeC(ushort_t* p, float v) { *p = f2bf(v); }

#define MFMA16(a, b, c) __builtin_amdgcn_mfma_f32_16x16x32_bf16(a, b, c, 0, 0, 0)

// One barrier per K-chunk: drain LDS ops only; global loads stay in flight.
#define LGKM_BARRIER()                                         \
    do {                                                       \
        asm volatile("s_waitcnt lgkmcnt(0)" ::: "memory");     \
        __builtin_amdgcn_s_barrier();                          \
    } while (0)

// Device-scope grid barrier (generation counting, no reset race).
// bar[0] = monotonically increasing arrival count, bar[1] = generation flag.
DEV void gridbar(int* bar, int gen) {
    __syncthreads();
    if (threadIdx.x == 0) {
        __threadfence();  // release: make this block's stores visible
        int t = __hip_atomic_fetch_add(&bar[0], 1, __ATOMIC_ACQ_REL,
                                       __HIP_MEMORY_SCOPE_AGENT);
        if (t == gen * GRIDN + (GRIDN - 1)) {
            __hip_atomic_store(&bar[1], gen + 1, __ATOMIC_RELEASE,
                               __HIP_MEMORY_SCOPE_AGENT);
        } else {
            while (__hip_atomic_load(&bar[1], __ATOMIC_ACQUIRE,
                                     __HIP_MEMORY_SCOPE_AGENT) < gen + 1) {
                __builtin_amdgcn_s_sleep(2);
            }
        }
        __threadfence();  // acquire side for non-atomic data
    }
    __syncthreads();
}

// ---------------------------------------------------------------------------
// prep_w: build bf16 W_enc_big [4096][1152], W_dec_pad [3072][1152] from fp32.
// ---------------------------------------------------------------------------
__global__ void prep_w(const float* __restrict__ W_hh_e, const float* __restrict__ W_ih_e,
                       const float* __restrict__ W_ih_d,
                       ushort_t* __restrict__ W_enc_big, ushort_t* __restrict__ W_dec_pad) {
    int idx = blockIdx.x * 256 + threadIdx.x;  // (G4+G3) * (KE/8)
    int n = idx / 144, kc = (idx - n * 144) * 8;
    ushort_t o[8];
    if (n < G4) {
        if (kc < HH) {
            if (n < G3) {
#pragma unroll
                for (int u = 0; u < 8; ++u) o[u] = f2bf(W_hh_e[(size_t)n * HH + kc + u]);
            } else {
#pragma unroll
                for (int u = 0; u < 8; ++u) o[u] = 0;
            }
        } else {
            int kk = kc - HH;
#pragma unroll
            for (int u = 0; u < 8; ++u) {
                int k2 = kk + u;
                ushort_t v = 0;
                if (k2 < EE) {
                    if (n < 2048) v = f2bf(W_ih_e[(size_t)n * EE + k2]);
                    else if (n >= G3) v = f2bf(W_ih_e[(size_t)(n - HH) * EE + k2]);
                }
                o[u] = v;
            }
        }
        *(int4*)(W_enc_big + (size_t)n * KE + kc) = *(int4*)o;
    } else {
        int nd = n - G4;
        if (kc < 128) {
#pragma unroll
            for (int u = 0; u < 8; ++u) {
                int k2 = kc + u;
                o[u] = (k2 < EE) ? f2bf(W_ih_d[(size_t)nd * 1124 + k2]) : (ushort_t)0;
            }
        } else {
#pragma unroll
            for (int u = 0; u < 8; ++u) o[u] = f2bf(W_ih_d[(size_t)nd * 1124 + EE + (kc - 128) + u]);
        }
        *(int4*)(W_dec_pad + (size_t)nd * KE + kc) = *(int4*)o;
    }
}

__global__ void conv_w(const float* __restrict__ W_hh_d, const float* __restrict__ W_fc,
                       ushort_t* __restrict__ W_hhd_b, ushort_t* __restrict__ W_fc_b) {
    int idx = blockIdx.x * 256 + threadIdx.x;
    const int N1 = G3 * HH / 8;
    const float* src;
    ushort_t* dst;
    size_t e;
    if (idx < N1) { e = (size_t)idx * 8; src = W_hh_d; dst = W_hhd_b; }
    else { e = (size_t)(idx - N1) * 8; src = W_fc; dst = W_fc_b; }
    float4 a = *(const float4*)(src + e);
    float4 b = *(const float4*)(src + e + 4);
    ushort_t o[8] = {f2bf(a.x), f2bf(a.y), f2bf(a.z), f2bf(a.w),
                     f2bf(b.x), f2bf(b.y), f2bf(b.z), f2bf(b.w)};
    *(int4*)(dst + e) = *(int4*)o;
}

// ---------------------------------------------------------------------------
// prep_x: emb_pad, A_enc0 = [h0 | emb_0], A_dec demb part, ce_sum = 0, bar = 0
// ---------------------------------------------------------------------------
__global__ void prep_x(const int* __restrict__ inputs, const int* __restrict__ targets,
                       const float* __restrict__ h0, const float* __restrict__ E_enc,
                       const float* __restrict__ E_dec,
                       ushort_t* __restrict__ emb_pad, ushort_t* __restrict__ A_enc,
                       ushort_t* __restrict__ A_dec,
                       float* __restrict__ ce_sum, int* __restrict__ bar) {
    int idx = blockIdx.x * 256 + threadIdx.x;
    const int R0 = SS * BB * 128;
    const int R1 = R0 + BB * KE;
    const int R2 = R1 + (TT - 1) * BB * 128;
    const int R3 = R2 + 96;
    if (idx < R0) {
        int s = idx >> 15;
        int r = idx & 32767;
        int b = r >> 7, k = r & 127;
        emb_pad[idx] = (k < EE) ? f2bf(E_enc[(size_t)inputs[b * SS + s] * EE + k]) : (ushort_t)0;
    } else if (idx < R1) {
        int i = idx - R0;
        int b = i / KE, c = i - b * KE;
        ushort_t v;
        if (c < HH) v = f2bf(h0[b * HH + c]);
        else { int kk = c - HH; v = (kk < EE) ? f2bf(E_enc[(size_t)inputs[b * SS] * EE + kk]) : (ushort_t)0; }
        A_enc[i] = v;
    } else if (idx < R2) {
        int i = idx - R1;
        int t = i >> 15;
        int r = i & 32767;
        int b = r >> 7, k = r & 127;
        int tok = (t == 0) ? 1 : targets[b * TT + t];
        A_dec[((size_t)(t * BB + b)) * KE + k] = (k < EE) ? f2bf(E_dec[(size_t)tok * EE + k]) : (ushort_t)0;
    } else if (idx < R2 + 32) {
        ce_sum[idx - R2] = 0.f;
    } else if (idx < R3) {
        bar[idx - R2 - 32] = 0;
    }
}

// ---------------------------------------------------------------------------
// PERSISTENT encoder: all 64 GRU steps in one launch. 128 blocks co-resident;
// device-scope grid barrier between steps. h kept in registers across steps.
// Per-step body identical to the verified enc_step (ping-pong LDS + lgkm-only
// barrier + XOR swizzle).
// ---------------------------------------------------------------------------
__global__ __launch_bounds__(256) void enc_all(
    ushort_t* __restrict__ A0, ushort_t* __restrict__ A1,
    const ushort_t* __restrict__ W, const float* __restrict__ bi,
    const float* __restrict__ bh, const float* __restrict__ h0,
    const ushort_t* __restrict__ emb_pad, const int* __restrict__ lengths,
    float* __restrict__ ctx_f, ushort_t* __restrict__ ctx_b, int* __restrict__ bar) {
    __shared__ ushort_t As[2][64 * 64];
    __shared__ float gbuf[4][64 * 33];
    int tid = threadIdx.x;
    int lane = tid & 63, g = tid >> 6;
    int j0 = blockIdx.x << 5, m0 = blockIdx.y << 6;
    int r16 = lane & 15, q = lane >> 4, q8 = q << 3;
    int srow = tid >> 3, skc = (tid & 7) << 3;
    const size_t offA = (size_t)(m0 + srow) * KE + skc;
    const int sx = (srow & 7) << 3;
    const int sw0 = (srow << 6) + (skc ^ sx);
    const int sw1 = ((srow + 32) << 6) + (skc ^ sx);
    const ushort_t* wb0 = W + (size_t)(g * 1024 + j0 + r16) * KE + q8;
    const ushort_t* wb1 = wb0 + (size_t)16 * KE;
    // epilogue mapping (step-invariant)
    int m = tid & 63, jc0 = (tid >> 6) << 3;
    int bgl = m0 + m, gj = j0 + jc0;
    int len1 = lengths[bgl] - 1;
    // biases hoisted (separate arrays: preserve original FP add order)
    float bir[8], bhr[8], biz[8], bhz[8], bhn[8], bin[8];
#pragma unroll
    for (int u = 0; u < 8; ++u) {
        int jg = gj + u;
        bir[u] = bi[jg];        bhr[u] = bh[jg];
        biz[u] = bi[1024 + jg]; bhz[u] = bh[1024 + jg];
        bhn[u] = bh[2048 + jg]; bin[u] = bi[2048 + jg];
    }
    // h in registers across all 64 steps
    float hreg[8];
#pragma unroll
    for (int u = 0; u < 8; ++u) hreg[u] = h0[(size_t)bgl * HH + gj + u];

    for (int s = 0; s < SS; ++s) {
        const ushort_t* Ain = (s & 1) ? A1 : A0;
        ushort_t* Aout = (s & 1) ? A0 : A1;
        const ushort_t* ap0 = Ain + offA;
        const ushort_t* ap1 = ap0 + (size_t)32 * KE;
        f32x4 zero = {0.f, 0.f, 0.f, 0.f};
        f32x4 acc[4][2];
#pragma unroll
        for (int i = 0; i < 4; ++i) { acc[i][0] = zero; acc[i][1] = zero; }
        int4 va0 = *(const int4*)(ap0);
        int4 va1 = *(const int4*)(ap1);
        bf16x8 wf00 = *(const bf16x8*)(wb0);
        bf16x8 wf01 = *(const bf16x8*)(wb1);
        bf16x8 wf10 = *(const bf16x8*)(wb0 + 32);
        bf16x8 wf11 = *(const bf16x8*)(wb1 + 32);
        *(int4*)(As[0] + sw0) = va0;
        *(int4*)(As[0] + sw1) = va1;
        va0 = *(const int4*)(ap0 + 64);
        va1 = *(const int4*)(ap1 + 64);
        __syncthreads();
        int p = 0;
        for (int k0 = 0; k0 < KE; k0 += 64) {
            int kn = k0 + 64;
            bf16x8 wn00, wn01, wn10, wn11;
            if (kn < KE) {
                *(int4*)(As[p ^ 1] + sw0) = va0;
                *(int4*)(As[p ^ 1] + sw1) = va1;
                if (kn + 64 < KE) {
                    va0 = *(const int4*)(ap0 + kn + 64);
                    va1 = *(const int4*)(ap1 + kn + 64);
                }
                wn00 = *(const bf16x8*)(wb0 + kn);
                wn01 = *(const bf16x8*)(wb1 + kn);
                wn10 = *(const bf16x8*)(wb0 + kn + 32);
                wn11 = *(const bf16x8*)(wb1 + kn + 32);
            }
            const ushort_t* Ab = As[p];
#pragma unroll
            for (int i = 0; i < 4; ++i) {
                int row = (i << 4) + r16;
                int xr = (row & 7) << 3;
                bf16x8 af0 = *(const bf16x8*)(Ab + (row << 6) + (q8 ^ xr));
                bf16x8 af1 = *(const bf16x8*)(Ab + (row << 6) + ((q8 + 32) ^ xr));
                acc[i][0] = MFMA16(af0, wf00, acc[i][0]);
                acc[i][1] = MFMA16(af0, wf01, acc[i][1]);
                acc[i][0] = MFMA16(af1, wf10, acc[i][0]);
                acc[i][1] = MFMA16(af1, wf11, acc[i][1]);
            }
            if (kn < KE) { wf00 = wn00; wf01 = wn01; wf10 = wn10; wf11 = wn11; }
            LGKM_BARRIER();
            p ^= 1;
        }
#pragma unroll
        for (int i = 0; i < 4; ++i)
#pragma unroll
            for (int j2 = 0; j2 < 2; ++j2)
#pragma unroll
                for (int r = 0; r < 4; ++r)
                    gbuf[g][(i * 16 + q * 4 + r) * 33 + j2 * 16 + r16] = acc[i][j2][r];
        __syncthreads();
        int sel = (len1 == s);
        const float* g0 = &gbuf[0][m * 33 + jc0];
        const float* g1 = &gbuf[1][m * 33 + jc0];
        const float* g2 = &gbuf[2][m * 33 + jc0];
        const float* g3 = &gbuf[3][m * 33 + jc0];
        ushort_t hb8[8];
#pragma unroll
        for (int u = 0; u < 8; ++u) {
            float rr = sigm(g0[u] + bir[u] + bhr[u]);
            float zz = sigm(g1[u] + biz[u] + bhz[u]);
            float hn = g2[u] + bhn[u];
            float inn = g3[u] + bin[u];
            float nn = tanhf(inn + rr * hn);
            float h2 = (1.f - zz) * nn + zz * hreg[u];
            hreg[u] = h2;
            hb8[u] = f2bf(h2);
        }
        *(int4*)(Aout + (size_t)bgl * KE + gj) = *(int4*)hb8;
        if (sel) {
            size_t hi = (size_t)bgl * 1024 + gj;
#pragma unroll
            for (int u = 0; u < 8; ++u) ctx_f[hi + u] = hreg[u];
            *(int4*)(ctx_b + hi) = *(int4*)hb8;
        }
        if (blockIdx.x == 0 && s + 1 < SS) {
            int rr2 = tid >> 2, c0 = (tid & 3) << 5;
#pragma unroll
            for (int cc = 0; cc < 32; cc += 8) {
                int4 v = *(const int4*)(emb_pad + ((size_t)(s + 1) * BB + m0 + rr2) * 128 + c0 + cc);
                *(int4*)(Aout + (size_t)(m0 + rr2) * KE + 1024 + c0 + cc) = v;
            }
        }
        if (s + 1 < SS) gridbar(bar, s);
    }
}

// Fill A_dec ctx columns for all 19 steps (decoder h-init comes from ctx_f/ctx_b)
__global__ void fill_ctx(const ushort_t* __restrict__ ctx_b, ushort_t* __restrict__ A_dec) {
    int idx = blockIdx.x * 256 + threadIdx.x;  // 19*256*1024
    int t = idx >> 18;
    int r = idx & 262143;
    int b = r >> 10;
    int k = r & 1023;
    A_dec[((size_t)(t * BB + b)) * KE + 128 + k] = ctx_b[r];
}

// ---------------------------------------------------------------------------
// 128x128 MFMA GEMM, ping-pong LDS + lgkm-only barrier + XOR swizzle.
// ---------------------------------------------------------------------------
template <typename OutT>
__global__ __launch_bounds__(256) void gemm128(const ushort_t* __restrict__ A,
                                               const ushort_t* __restrict__ W,
                                               OutT* __restrict__ C,
                                               int K, int lda, int ldw, int ldc) {
    __shared__ ushort_t As[2][128 * 32];
    __shared__ ushort_t Bs[2][128 * 32];
    int tid = threadIdx.x;
    int lane = tid & 63, wave = tid >> 6;
    int m0 = blockIdx.y << 7, n0 = blockIdx.x << 7;
    int row0 = tid >> 2, kc0 = (tid & 3) << 3;
    const ushort_t* a0p = A + (size_t)(m0 + row0) * lda + kc0;
    const ushort_t* a1p = A + (size_t)(m0 + row0 + 64) * lda + kc0;
    const ushort_t* w0p = W + (size_t)(n0 + row0) * ldw + kc0;
    const ushort_t* w1p = W + (size_t)(n0 + row0 + 64) * ldw + kc0;
    int mq = (wave >> 1) << 6, nq = (wave & 1) << 6;
    int r16 = lane & 15, q8 = (lane >> 4) << 3;
    const int sx = ((row0 >> 1) & 3) << 3;
    const int sw0 = (row0 << 5) + (kc0 ^ sx);
    const int sw1 = ((row0 + 64) << 5) + (kc0 ^ sx);
    f32x4 zero4 = {0.f, 0.f, 0.f, 0.f};
    f32x4 acc[4][4];
#pragma unroll
    for (int i = 0; i < 4; ++i)
#pragma unroll
        for (int j = 0; j < 4; ++j) acc[i][j] = zero4;
    int4 va0 = *(const int4*)(a0p);
    int4 va1 = *(const int4*)(a1p);
    int4 vb0 = *(const int4*)(w0p);
    int4 vb1 = *(const int4*)(w1p);
    *(int4*)(As[0] + sw0) = va0;
    *(int4*)(As[0] + sw1) = va1;
    *(int4*)(Bs[0] + sw0) = vb0;
    *(int4*)(Bs[0] + sw1) = vb1;
    va0 = *(const int4*)(a0p + 32);
    va1 = *(const int4*)(a1p + 32);
    vb0 = *(const int4*)(w0p + 32);
    vb1 = *(const int4*)(w1p + 32);
    __syncthreads();
    int p = 0;
    for (int k0 = 0; k0 < K; k0 += 32) {
        int kn = k0 + 32;
        if (kn < K) {
            *(int4*)(As[p ^ 1] + sw0) = va0;
            *(int4*)(As[p ^ 1] + sw1) = va1;
            *(int4*)(Bs[p ^ 1] + sw0) = vb0;
            *(int4*)(Bs[p ^ 1] + sw1) = vb1;
            if (kn + 32 < K) {
                va0 = *(const int4*)(a0p + kn + 32);
                va1 = *(const int4*)(a1p + kn + 32);
                vb0 = *(const int4*)(w0p + kn + 32);
                vb1 = *(const int4*)(w1p + kn + 32);
            }
        }
        bf16x8 af[4], bfv[4];
#pragma unroll
        for (int i = 0; i < 4; ++i) {
            int ar = mq + i * 16 + r16;
            af[i] = *(const bf16x8*)(As[p] + (ar << 5) + (q8 ^ ((((ar) >> 1) & 3) << 3)));
        }
#pragma unroll
        for (int j = 0; j < 4; ++j) {
            int br = nq + j * 16 + r16;
            bfv[j] = *(const bf16x8*)(Bs[p] + (br << 5) + (q8 ^ ((((br) >> 1) & 3) << 3)));
        }
#pragma unroll
        for (int i = 0; i < 4; ++i)
#pragma unroll
            for (int j = 0; j < 4; ++j) acc[i][j] = MFMA16(af[i], bfv[j], acc[i][j]);
        LGKM_BARRIER();
        p ^= 1;
    }
    int rbase = (lane >> 4) << 2;
#pragma unroll
    for (int i = 0; i < 4; ++i)
#pragma unroll
        for (int j = 0; j < 4; ++j)
#pragma unroll
            for (int r = 0; r < 4; ++r)
                storeC(&C[(size_t)(m0 + mq + i * 16 + rbase + r) * ldc + (n0 + nq + j * 16 + r16)],
                       acc[i][j][r]);
}

// ---------------------------------------------------------------------------
// PERSISTENT decoder: all 19 GRU steps in one launch (3 gate groups; wave 3
// stages/epilogues only). h in registers; writes H_all[t] each step.
// ---------------------------------------------------------------------------
__global__ __launch_bounds__(256) void dec_all(
    const ushort_t* __restrict__ ctx_b, ushort_t* __restrict__ H_all,
    const ushort_t* __restrict__ W, const ushort_t* __restrict__ gi_all,
    const float* __restrict__ bi, const float* __restrict__ bh,
    const float* __restrict__ ctx_f, int* __restrict__ bar) {
    __shared__ ushort_t As[2][64 * 64];
    __shared__ float gbuf[3][64 * 33];
    int tid = threadIdx.x;
    int lane = tid & 63, g = tid >> 6;
    int j0 = blockIdx.x << 5, m0 = blockIdx.y << 6;
    int r16 = lane & 15, q = lane >> 4, q8 = q << 3;
    int srow = tid >> 3, skc = (tid & 7) << 3;
    const size_t offA = (size_t)(m0 + srow) * HH + skc;
    const int sx = (srow & 7) << 3;
    const int sw0 = (srow << 6) + (skc ^ sx);
    const int sw1 = ((srow + 32) << 6) + (skc ^ sx);
    const ushort_t* wb0 = W + (size_t)(g * 1024 + j0 + r16) * HH + q8;
    const ushort_t* wb1 = wb0 + (size_t)16 * HH;
    int m = tid & 63, jc0 = (tid >> 6) << 3;
    int bgl = m0 + m, gj = j0 + jc0;
    float bir[8], bhr[8], biz[8], bhz[8], bhn[8], bin[8];
#pragma unroll
    for (int u = 0; u < 8; ++u) {
        int jg = gj + u;
        bir[u] = bi[jg];        bhr[u] = bh[jg];
        biz[u] = bi[1024 + jg]; bhz[u] = bh[1024 + jg];
        bhn[u] = bh[2048 + jg]; bin[u] = bi[2048 + jg];
    }
    float hreg[8];
#pragma unroll
    for (int u = 0; u < 8; ++u) hreg[u] = ctx_f[(size_t)bgl * HH + gj + u];

    for (int t = 0; t < TT - 1; ++t) {
        const ushort_t* Ain = t ? (H_all + (size_t)(t - 1) * BB * HH) : ctx_b;
        ushort_t* Aout = H_all + (size_t)t * BB * HH;
        const ushort_t* ap0 = Ain + offA;
        const ushort_t* ap1 = ap0 + (size_t)32 * HH;
        const ushort_t* gip = gi_all + (size_t)t * BB * G3 + (size_t)bgl * G3;
        f32x4 zero = {0.f, 0.f, 0.f, 0.f};
        f32x4 acc[4][2];
#pragma unroll
        for (int i = 0; i < 4; ++i) { acc[i][0] = zero; acc[i][1] = zero; }
        int4 va0 = *(const int4*)(ap0);
        int4 va1 = *(const int4*)(ap1);
        bf16x8 wf00 = {0, 0, 0, 0, 0, 0, 0, 0}, wf01 = wf00, wf10 = wf00, wf11 = wf00;
        if (g < 3) {
            wf00 = *(const bf16x8*)(wb0);
            wf01 = *(const bf16x8*)(wb1);
            wf10 = *(const bf16x8*)(wb0 + 32);
            wf11 = *(const bf16x8*)(wb1 + 32);
        }
        *(int4*)(As[0] + sw0) = va0;
        *(int4*)(As[0] + sw1) = va1;
        va0 = *(const int4*)(ap0 + 64);
        va1 = *(const int4*)(ap1 + 64);
        __syncthreads();
        int p = 0;
        for (int k0 = 0; k0 < HH; k0 += 64) {
            int kn = k0 + 64;
            bf16x8 wn00, wn01, wn10, wn11;
            if (kn < HH) {
                *(int4*)(As[p ^ 1] + sw0) = va0;
                *(int4*)(As[p ^ 1] + sw1) = va1;
                if (kn + 64 < HH) {
                    va0 = *(const int4*)(ap0 + kn + 64);
                    va1 = *(const int4*)(ap1 + kn + 64);
                }
                if (g < 3) {
                    wn00 = *(const bf16x8*)(wb0 + kn);
                    wn01 = *(const bf16x8*)(wb1 + kn);
                    wn10 = *(const bf16x8*)(wb0 + kn + 32);
                    wn11 = *(const bf16x8*)(wb1 + kn + 32);
                }
            }
            if (g < 3) {
                const ushort_t* Ab = As[p];
#pragma unroll
                for (int i = 0; i < 4; ++i) {
                    int row = (i << 4) + r16;
                    int xr = (row & 7) << 3;
                    bf16x8 af0 = *(const bf16x8*)(Ab + (row << 6) + (q8 ^ xr));
                    bf16x8 af1 = *(const bf16x8*)(Ab + (row << 6) + ((q8 + 32) ^ xr));
                    acc[i][0] = MFMA16(af0, wf00, acc[i][0]);
                    acc[i][1] = MFMA16(af0, wf01, acc[i][1]);
                    acc[i][0] = MFMA16(af1, wf10, acc[i][0]);
                    acc[i][1] = MFMA16(af1, wf11, acc[i][1]);
                }
                if (kn < HH) { wf00 = wn00; wf01 = wn01; wf10 = wn10; wf11 = wn11; }
            }
            LGKM_BARRIER();
            p ^= 1;
        }
        if (g < 3) {
#pragma unroll
            for (int i = 0; i < 4; ++i)
#pragma unroll
                for (int j2 = 0; j2 < 2; ++j2)
#pragma unroll
                    for (int r = 0; r < 4; ++r)
                        gbuf[g][(i * 16 + q * 4 + r) * 33 + j2 * 16 + r16] = acc[i][j2][r];
        }
        __syncthreads();
        ushort_t gr[8], gz[8], gn[8], hb8[8];
        *(int4*)gr = *(const int4*)(gip + gj);
        *(int4*)gz = *(const int4*)(gip + 1024 + gj);
        *(int4*)gn = *(const int4*)(gip + 2048 + gj);
        const float* g0 = &gbuf[0][m * 33 + jc0];
        const float* g1 = &gbuf[1][m * 33 + jc0];
        const float* g2 = &gbuf[2][m * 33 + jc0];
#pragma unroll
        for (int u = 0; u < 8; ++u) {
            float rr = sigm(g0[u] + bhr[u] + bf2f(gr[u]) + bir[u]);
            float zz = sigm(g1[u] + bhz[u] + bf2f(gz[u]) + biz[u]);
            float hn = g2[u] + bhn[u];
            float inn = bf2f(gn[u]) + bin[u];
            float nn = tanhf(inn + rr * hn);
            float h2 = (1.f - zz) * nn + zz * hreg[u];
            hreg[u] = h2;
            hb8[u] = f2bf(h2);
        }
        *(int4*)(Aout + (size_t)bgl * 1024 + gj) = *(int4*)hb8;
        if (t + 1 < TT - 1) gridbar(bar + 16, t);
    }
}

// ---------------------------------------------------------------------------
// BATCHED fused logits GEMM + CE partials, XCD-chunked: each XCD owns 5
// m-tiles (A slice ~1.25 MB, L2-resident) and streams all 250 n-panels,
// m-local fastest (W panel fetched once per XCD, reused 5x from L2).
// bid -> xcd = bid&7 (round-robin XCD map), slot = bid>>3,
// n_t = slot/5, m_t = xcd*5 + slot%5 (skip m_t >= 38).
// ---------------------------------------------------------------------------
__global__ __launch_bounds__(256) void logits_ce(
    const ushort_t* __restrict__ A, const ushort_t* __restrict__ Wf,
    const float* __restrict__ bfc, const int* __restrict__ targets,
    float* __restrict__ part_max, float* __restrict__ part_sum,
    float* __restrict__ xt) {
    int bid = blockIdx.x;
    int xcd = bid & 7;
    int slot = bid >> 3;
    int n_t = slot / 5;
    int m_t = xcd * 5 + (slot - n_t * 5);
    if (m_t >= (TT - 1) * BB / 128) return;
    __shared__ ushort_t As[2][128 * 32];
    __shared__ ushort_t Bs[2][128 * 32];
    __shared__ float wm[128][2], ws2[128][2];
    int tid = threadIdx.x;
    int lane = tid & 63, wave = tid >> 6;
    int m0 = m_t << 7, n0 = n_t << 7;
    int row0 = tid >> 2, kc0 = (tid & 3) << 3;
    const ushort_t* a0p = A + (size_t)(m0 + row0) * HH + kc0;
    const ushort_t* a1p = A + (size_t)(m0 + row0 + 64) * HH + kc0;
    const ushort_t* w0p = Wf + (size_t)(n0 + row0) * HH + kc0;
    const ushort_t* w1p = Wf + (size_t)(n0 + row0 + 64) * HH + kc0;
    int mq = (wave >> 1) << 6, nq = (wave & 1) << 6;
    int r16 = lane & 15, q = lane >> 4, q8 = q << 3;
    const int sx = ((row0 >> 1) & 3) << 3;
    const int sw0 = (row0 << 5) + (kc0 ^ sx);
    const int sw1 = ((row0 + 64) << 5) + (kc0 ^ sx);
    f32x4 zero4 = {0.f, 0.f, 0.f, 0.f};
    f32x4 acc[4][4];
#pragma unroll
    for (int i = 0; i < 4; ++i)
#pragma unroll
        for (int j = 0; j < 4; ++j) acc[i][j] = zero4;
    int4 va0 = *(const int4*)(a0p);
    int4 va1 = *(const int4*)(a1p);
    int4 vb0 = *(const int4*)(w0p);
    int4 vb1 = *(const int4*)(w1p);
    *(int4*)(As[0] + sw0) = va0;
    *(int4*)(As[0] + sw1) = va1;
    *(int4*)(Bs[0] + sw0) = vb0;
    *(int4*)(Bs[0] + sw1) = vb1;
    va0 = *(const int4*)(a0p + 32);
    va1 = *(const int4*)(a1p + 32);
    vb0 = *(const int4*)(w0p + 32);
    vb1 = *(const int4*)(w1p + 32);
    __syncthreads();
    int p = 0;
    for (int k0 = 0; k0 < HH; k0 += 32) {
        int kn = k0 + 32;
        if (kn < HH) {
            *(int4*)(As[p ^ 1] + sw0) = va0;
            *(int4*)(As[p ^ 1] + sw1) = va1;
            *(int4*)(Bs[p ^ 1] + sw0) = vb0;
            *(int4*)(Bs[p ^ 1] + sw1) = vb1;
            if (kn + 32 < HH) {
                va0 = *(const int4*)(a0p + kn + 32);
                va1 = *(const int4*)(a1p + kn + 32);
                vb0 = *(const int4*)(w0p + kn + 32);
                vb1 = *(const int4*)(w1p + kn + 32);
            }
        }
        bf16x8 af[4], bfv[4];
#pragma unroll
        for (int i = 0; i < 4; ++i) {
            int ar = mq + i * 16 + r16;
            af[i] = *(const bf16x8*)(As[p] + (ar << 5) + (q8 ^ ((((ar) >> 1) & 3) << 3)));
        }
#pragma unroll
        for (int j = 0; j < 4; ++j) {
            int br = nq + j * 16 + r16;
            bfv[j] = *(const bf16x8*)(Bs[p] + (br << 5) + (q8 ^ ((((br) >> 1) & 3) << 3)));
        }
#pragma unroll
        for (int i = 0; i < 4; ++i)
#pragma unroll
            for (int j = 0; j < 4; ++j) acc[i][j] = MFMA16(af[i], bfv[j], acc[i][j]);
        LGKM_BARRIER();
        p ^= 1;
    }
    float bias[4];
#pragma unroll
    for (int j2 = 0; j2 < 4; ++j2) bias[j2] = bfc[n0 + nq + j2 * 16 + r16];
    int nw = wave & 1;
#pragma unroll
    for (int i = 0; i < 4; ++i) {
#pragma unroll
        for (int r = 0; r < 4; ++r) {
            int rloc = mq + i * 16 + q * 4 + r;
            int brow = m0 + rloc;
            int y = targets[(brow & 255) * TT + (brow >> 8) + 1];
            float v[4];
            float mx = -3.0e38f;
#pragma unroll
            for (int j2 = 0; j2 < 4; ++j2) {
                v[j2] = acc[i][j2][r] + bias[j2];
                if (n0 + nq + j2 * 16 + r16 == y) xt[brow] = v[j2];
                mx = fmaxf(mx, v[j2]);
            }
#pragma unroll
            for (int d = 1; d < 16; d <<= 1) mx = fmaxf(mx, __shfl_xor(mx, d, 64));
            float se = 0.f;
#pragma unroll
            for (int j2 = 0; j2 < 4; ++j2) se += expf(v[j2] - mx);
#pragma unroll
            for (int d = 1; d < 16; d <<= 1) se += __shfl_xor(se, d, 64);
            if (r16 == 0) { wm[rloc][nw] = mx; ws2[rloc][nw] = se; }
        }
    }
    __syncthreads();
    if (tid < 128) {
        float m0v = wm[tid][0], m1v = wm[tid][1];
        float M = fmaxf(m0v, m1v);
        float S = ws2[tid][0] * expf(m0v - M) + ws2[tid][1] * expf(m1v - M);
        int brow = m0 + tid;
        part_max[(size_t)brow * 256 + n_t] = M;
        part_sum[(size_t)brow * 256 + n_t] = S;
    }
}

// Merge 250 per-row partials -> CE for all 4864 rows; atomicAdd ce_sum[t]
__global__ void ce_merge(const float* __restrict__ pm, const float* __restrict__ ps,
                         const float* __restrict__ xt, float* __restrict__ ce_sum) {
    int row = blockIdx.x * 4 + (threadIdx.x >> 6);
    int lane = threadIdx.x & 63;
    const float* pmr = pm + (size_t)row * 256;
    const float* psr = ps + (size_t)row * 256;
    float lm[4];
    int cnt = 0;
    float mx = -3.0e38f;
    for (int i = lane; i < 250; i += 64) { float v = pmr[i]; lm[cnt++] = v; mx = fmaxf(mx, v); }
    for (int d = 1; d < 64; d <<= 1) mx = fmaxf(mx, __shfl_xor(mx, d, 64));
    float s = 0.f;
    cnt = 0;
    for (int i = lane; i < 250; i += 64) { s += psr[i] * expf(lm[cnt++] - mx); }
    for (int d = 1; d < 64; d <<= 1) s += __shfl_xor(s, d, 64);
    if (lane == 0) atomicAdd(&ce_sum[row >> 8], mx + logf(s) - xt[row]);
}

// loss = (1/T) * sum_t (ce_sum[t]/B) * (mask_sum[t]/B)
__global__ void finalize(const float* __restrict__ ce_sum, const int* __restrict__ targets,
                         float* __restrict__ out) {
    int lane = threadIdx.x;
    float term = 0.f;
    if (lane < TT - 1) {
        int msum = 0;
        for (int b = 0; b < BB; ++b) msum += (targets[b * TT + lane + 1] >= 1) ? 1 : 0;
        term = (ce_sum[lane] * (1.f / BB)) * ((float)msum * (1.f / BB));
    }
    for (int off = 32; off > 0; off >>= 1) term += __shfl_down(term, off, 64);
    if (lane == 0) out[0] = term * (1.f / TT);
}

extern "C" void kernel_launch(void* const* d_in, const int* in_sizes, int n_in,
                              void* d_out, int out_size, void* d_ws, size_t ws_size,
                              hipStream_t stream) {
    const int* inputs = (const int*)d_in[0];
    const int* targets = (const int*)d_in[1];
    const int* lengths = (const int*)d_in[2];
    const float* h0 = (const float*)d_in[3];
    const float* E_enc = (const float*)d_in[4];
    const float* E_dec = (const float*)d_in[5];
    const float* W_ih_e = (const float*)d_in[6];
    const float* W_hh_e = (const float*)d_in[7];
    const float* b_ih_e = (const float*)d_in[8];
    const float* b_hh_e = (const float*)d_in[9];
    const float* W_ih_d = (const float*)d_in[10];
    const float* W_hh_d = (const float*)d_in[11];
    const float* b_ih_d = (const float*)d_in[12];
    const float* b_hh_d = (const float*)d_in[13];
    const float* W_fc = (const float*)d_in[14];
    const float* b_fc = (const float*)d_in[15];

    char* ws = (char*)d_ws;
    size_t off = 0;
    auto alloc = [&](size_t bytes) -> char* {
        char* p = ws + off;
        off += (bytes + 255) & ~(size_t)255;
        return p;
    };
    const int MROWS = (TT - 1) * BB;  // 4864
    ushort_t* W_enc_big = (ushort_t*)alloc((size_t)G4 * KE * 2);
    ushort_t* W_dec_pad = (ushort_t*)alloc((size_t)G3 * KE * 2);
    ushort_t* W_hhd_b = (ushort_t*)alloc((size_t)G3 * HH * 2);
    ushort_t* W_fc_b = (ushort_t*)alloc((size_t)VV * HH * 2);
    ushort_t* emb_pad = (ushort_t*)alloc((size_t)SS * BB * 128 * 2);
    ushort_t* A_enc0 = (ushort_t*)alloc((size_t)BB * KE * 2);
    ushort_t* A_enc1 = (ushort_t*)alloc((size_t)BB * KE * 2);
    ushort_t* A_dec = (ushort_t*)alloc((size_t)MROWS * KE * 2);
    ushort_t* gi_dec = (ushort_t*)alloc((size_t)MROWS * G3 * 2);
    ushort_t* H_all = (ushort_t*)alloc((size_t)MROWS * HH * 2);
    float* ctx_f = (float*)alloc((size_t)BB * HH * 4);
    ushort_t* ctx_b = (ushort_t*)alloc((size_t)BB * HH * 2);
    float* part_max = (float*)alloc((size_t)MROWS * 256 * 4);
    float* part_sum = (float*)alloc((size_t)MROWS * 256 * 4);
    float* xt = (float*)alloc((size_t)MROWS * 4);
    float* ce_sum = (float*)alloc(64 * 4);
    int* bar = (int*)alloc(64 * 4);

    // ---- prep ----
    prep_w<<<(G4 + G3) * (KE / 8) / 256, 256, 0, stream>>>(W_hh_e, W_ih_e, W_ih_d,
                                                           W_enc_big, W_dec_pad);
    conv_w<<<(G3 * HH + VV * HH) / 8 / 256, 256, 0, stream>>>(W_hh_d, W_fc, W_hhd_b, W_fc_b);
    {
        int nx = SS * BB * 128 + BB * KE + (TT - 1) * BB * 128 + 96;
        prep_x<<<(nx + 255) / 256, 256, 0, stream>>>(inputs, targets, h0, E_enc, E_dec,
                                                     emb_pad, A_enc0, A_dec, ce_sum, bar);
    }

    // ---- encoder: ONE persistent launch, 64 steps with grid barriers ----
    enc_all<<<dim3(32, 4), 256, 0, stream>>>(A_enc0, A_enc1, W_enc_big, b_ih_e, b_hh_e,
                                             h0, emb_pad, lengths, ctx_f, ctx_b, bar);

    // ---- decoder input-side gates: one big GEMM ----
    fill_ctx<<<((TT - 1) * BB * HH) / 256, 256, 0, stream>>>(ctx_b, A_dec);
    gemm128<ushort_t><<<dim3(G3 / 128, MROWS / 128), 256, 0, stream>>>(
        A_dec, W_dec_pad, gi_dec, KE, KE, KE, G3);

    // ---- decoder: ONE persistent launch, 19 steps writing H_all ----
    dec_all<<<dim3(32, 4), 256, 0, stream>>>(ctx_b, H_all, W_hhd_b, gi_dec,
                                             b_ih_d, b_hh_d, ctx_f, bar);

    // ---- ONE batched logits+CE over all 19 steps (XCD-chunked), one merge ----
    logits_ce<<<10000, 256, 0, stream>>>(H_all, W_fc_b, b_fc, targets,
                                         part_max, part_sum, xt);
    ce_merge<<<MROWS / 4, 256, 0, stream>>>(part_max, part_sum, xt, ce_sum);

    finalize<<<1, 64, 0, stream>>>(ce_sum, targets, (float*)d_out);
}

// Round 3
// 2609.778 us; speedup vs baseline: 1.2782x; 1.2782x over previous
//
#include <hip/hip_runtime.h>
#include <stdint.h>

#define BB 256
#define SS 64
#define TT 20
#define HH 1024
#define EE 100
#define G3 3072
#define G4 4096
#define KE 1152     // 1024 + 128 (E padded to 128)
#define VV 32000
#define GRIDN 128   // blocks in persistent recurrent kernels (<= 256 CUs)

typedef unsigned short ushort_t;
typedef unsigned long long u64_t;
typedef short bf16x8 __attribute__((ext_vector_type(8)));
typedef float f32x4 __attribute__((ext_vector_type(4)));

#define DEV static __device__ __forceinline__

DEV float bf2f(ushort_t h) {
    union { uint32_t u; float f; } c; c.u = ((uint32_t)h) << 16; return c.f;
}
DEV ushort_t f2bf(float x) {
    union { float f; uint32_t u; } c; c.f = x;
    uint32_t r = (c.u + 0x7fffu + ((c.u >> 16) & 1u)) >> 16;
    return (ushort_t)r;
}
DEV float sigm(float x) { return 1.f / (1.f + expf(-x)); }

DEV void storeC(float* p, float v) { *p = v; }
DEV void storeC(ushort_t* p, float v) { *p = f2bf(v); }

// Relaxed agent-scope (sc1, LLC-coherent) 8B accesses for cross-XCD data.
DEV u64_t ald(const void* p) {
    return __hip_atomic_load((const u64_t*)p, __ATOMIC_RELAXED, __HIP_MEMORY_SCOPE_AGENT);
}
DEV void ast(void* p, u64_t v) {
    __hip_atomic_store((u64_t*)p, v, __ATOMIC_RELAXED, __HIP_MEMORY_SCOPE_AGENT);
}

#define MFMA16(a, b, c) __builtin_amdgcn_mfma_f32_16x16x32_bf16(a, b, c, 0, 0, 0)

// One barrier per K-chunk: drain LDS ops only; global loads stay in flight.
#define LGKM_BARRIER()                                         \
    do {                                                       \
        asm volatile("s_waitcnt lgkmcnt(0)" ::: "memory");     \
        __builtin_amdgcn_s_barrier();                          \
    } while (0)

// Fence-free grid barrier: monotone counter, RELEASE arrive, RELAXED poll.
// All inter-block data uses sc1 (agent-scope relaxed atomics), so no L2
// invalidate is needed -> W stays L2-resident across steps.
DEV void gridbar(int* bar, int target) {
    __syncthreads();  // drains each wave's vmcnt -> sc1 stores LLC-visible
    if (threadIdx.x == 0) {
        __hip_atomic_fetch_add(bar, 1, __ATOMIC_RELEASE, __HIP_MEMORY_SCOPE_AGENT);
        while (__hip_atomic_load(bar, __ATOMIC_RELAXED, __HIP_MEMORY_SCOPE_AGENT) < target)
            __builtin_amdgcn_s_sleep(4);
    }
    __syncthreads();
    asm volatile("" ::: "memory");
}

// ---------------------------------------------------------------------------
// prep_w: build bf16 W_enc_big [4096][1152], W_dec_pad [3072][1152] from fp32.
// ---------------------------------------------------------------------------
__global__ void prep_w(const float* __restrict__ W_hh_e, const float* __restrict__ W_ih_e,
                       const float* __restrict__ W_ih_d,
                       ushort_t* __restrict__ W_enc_big, ushort_t* __restrict__ W_dec_pad) {
    int idx = blockIdx.x * 256 + threadIdx.x;  // (G4+G3) * (KE/8)
    int n = idx / 144, kc = (idx - n * 144) * 8;
    ushort_t o[8];
    if (n < G4) {
        if (kc < HH) {
            if (n < G3) {
#pragma unroll
                for (int u = 0; u < 8; ++u) o[u] = f2bf(W_hh_e[(size_t)n * HH + kc + u]);
            } else {
#pragma unroll
                for (int u = 0; u < 8; ++u) o[u] = 0;
            }
        } else {
            int kk = kc - HH;
#pragma unroll
            for (int u = 0; u < 8; ++u) {
                int k2 = kk + u;
                ushort_t v = 0;
                if (k2 < EE) {
                    if (n < 2048) v = f2bf(W_ih_e[(size_t)n * EE + k2]);
                    else if (n >= G3) v = f2bf(W_ih_e[(size_t)(n - HH) * EE + k2]);
                }
                o[u] = v;
            }
        }
        *(int4*)(W_enc_big + (size_t)n * KE + kc) = *(int4*)o;
    } else {
        int nd = n - G4;
        if (kc < 128) {
#pragma unroll
            for (int u = 0; u < 8; ++u) {
                int k2 = kc + u;
                o[u] = (k2 < EE) ? f2bf(W_ih_d[(size_t)nd * 1124 + k2]) : (ushort_t)0;
            }
        } else {
#pragma unroll
            for (int u = 0; u < 8; ++u) o[u] = f2bf(W_ih_d[(size_t)nd * 1124 + EE + (kc - 128) + u]);
        }
        *(int4*)(W_dec_pad + (size_t)nd * KE + kc) = *(int4*)o;
    }
}

__global__ void conv_w(const float* __restrict__ W_hh_d, const float* __restrict__ W_fc,
                       ushort_t* __restrict__ W_hhd_b, ushort_t* __restrict__ W_fc_b) {
    int idx = blockIdx.x * 256 + threadIdx.x;
    const int N1 = G3 * HH / 8;
    const float* src;
    ushort_t* dst;
    size_t e;
    if (idx < N1) { e = (size_t)idx * 8; src = W_hh_d; dst = W_hhd_b; }
    else { e = (size_t)(idx - N1) * 8; src = W_fc; dst = W_fc_b; }
    float4 a = *(const float4*)(src + e);
    float4 b = *(const float4*)(src + e + 4);
    ushort_t o[8] = {f2bf(a.x), f2bf(a.y), f2bf(a.z), f2bf(a.w),
                     f2bf(b.x), f2bf(b.y), f2bf(b.z), f2bf(b.w)};
    *(int4*)(dst + e) = *(int4*)o;
}

// ---------------------------------------------------------------------------
// prep_x: emb_pad, A_enc0 = [h0 | emb_0], A_dec demb part, ce_sum = 0, bar = 0
// ---------------------------------------------------------------------------
__global__ void prep_x(const int* __restrict__ inputs, const int* __restrict__ targets,
                       const float* __restrict__ h0, const float* __restrict__ E_enc,
                       const float* __restrict__ E_dec,
                       ushort_t* __restrict__ emb_pad, ushort_t* __restrict__ A_enc,
                       ushort_t* __restrict__ A_dec,
                       float* __restrict__ ce_sum, int* __restrict__ bar) {
    int idx = blockIdx.x * 256 + threadIdx.x;
    const int R0 = SS * BB * 128;
    const int R1 = R0 + BB * KE;
    const int R2 = R1 + (TT - 1) * BB * 128;
    const int R3 = R2 + 96;
    if (idx < R0) {
        int s = idx >> 15;
        int r = idx & 32767;
        int b = r >> 7, k = r & 127;
        emb_pad[idx] = (k < EE) ? f2bf(E_enc[(size_t)inputs[b * SS + s] * EE + k]) : (ushort_t)0;
    } else if (idx < R1) {
        int i = idx - R0;
        int b = i / KE, c = i - b * KE;
        ushort_t v;
        if (c < HH) v = f2bf(h0[b * HH + c]);
        else { int kk = c - HH; v = (kk < EE) ? f2bf(E_enc[(size_t)inputs[b * SS] * EE + kk]) : (ushort_t)0; }
        A_enc[i] = v;
    } else if (idx < R2) {
        int i = idx - R1;
        int t = i >> 15;
        int r = i & 32767;
        int b = r >> 7, k = r & 127;
        int tok = (t == 0) ? 1 : targets[b * TT + t];
        A_dec[((size_t)(t * BB + b)) * KE + k] = (k < EE) ? f2bf(E_dec[(size_t)tok * EE + k]) : (ushort_t)0;
    } else if (idx < R2 + 32) {
        ce_sum[idx - R2] = 0.f;
    } else if (idx < R3) {
        bar[idx - R2 - 32] = 0;
    }
}

// ---------------------------------------------------------------------------
// PERSISTENT encoder: all 64 GRU steps in one launch, fence-free grid barrier.
// Cross-step data (A buffers, ctx) via sc1 relaxed atomics; W/bias/emb stay
// L2-resident. h kept in registers across steps.
// ---------------------------------------------------------------------------
__global__ __launch_bounds__(256) void enc_all(
    ushort_t* __restrict__ A0, ushort_t* __restrict__ A1,
    const ushort_t* __restrict__ W, const float* __restrict__ bi,
    const float* __restrict__ bh, const float* __restrict__ h0,
    const ushort_t* __restrict__ emb_pad, const int* __restrict__ lengths,
    float* __restrict__ ctx_f, ushort_t* __restrict__ ctx_b, int* __restrict__ bar) {
    __shared__ ushort_t As[2][64 * 64];
    __shared__ float gbuf[4][64 * 33];
    int tid = threadIdx.x;
    int lane = tid & 63, g = tid >> 6;
    int j0 = blockIdx.x << 5, m0 = blockIdx.y << 6;
    int r16 = lane & 15, q = lane >> 4, q8 = q << 3;
    int srow = tid >> 3, skc = (tid & 7) << 3;
    const size_t offA = (size_t)(m0 + srow) * KE + skc;
    const int sx = (srow & 7) << 3;
    const int sw0 = (srow << 6) + (skc ^ sx);
    const int sw1 = ((srow + 32) << 6) + (skc ^ sx);
    const ushort_t* wb0 = W + (size_t)(g * 1024 + j0 + r16) * KE + q8;
    const ushort_t* wb1 = wb0 + (size_t)16 * KE;
    int m = tid & 63, jc0 = (tid >> 6) << 3;
    int bgl = m0 + m, gj = j0 + jc0;
    int len1 = lengths[bgl] - 1;
    float bir[8], bhr[8], biz[8], bhz[8], bhn[8], bin[8];
#pragma unroll
    for (int u = 0; u < 8; ++u) {
        int jg = gj + u;
        bir[u] = bi[jg];        bhr[u] = bh[jg];
        biz[u] = bi[1024 + jg]; bhz[u] = bh[1024 + jg];
        bhn[u] = bh[2048 + jg]; bin[u] = bi[2048 + jg];
    }
    float hreg[8];
#pragma unroll
    for (int u = 0; u < 8; ++u) hreg[u] = h0[(size_t)bgl * HH + gj + u];

    for (int s = 0; s < SS; ++s) {
        const ushort_t* Ain = (s & 1) ? A1 : A0;
        ushort_t* Aout = (s & 1) ? A0 : A1;
        const ushort_t* ap0 = Ain + offA;
        const ushort_t* ap1 = ap0 + (size_t)32 * KE;
        f32x4 zero = {0.f, 0.f, 0.f, 0.f};
        f32x4 acc[4][2];
#pragma unroll
        for (int i = 0; i < 4; ++i) { acc[i][0] = zero; acc[i][1] = zero; }
        u64_t va0a = ald(ap0), va0b = ald(ap0 + 4);
        u64_t va1a = ald(ap1), va1b = ald(ap1 + 4);
        bf16x8 wf00 = *(const bf16x8*)(wb0);
        bf16x8 wf01 = *(const bf16x8*)(wb1);
        bf16x8 wf10 = *(const bf16x8*)(wb0 + 32);
        bf16x8 wf11 = *(const bf16x8*)(wb1 + 32);
        *(u64_t*)(As[0] + sw0) = va0a; *(u64_t*)(As[0] + sw0 + 4) = va0b;
        *(u64_t*)(As[0] + sw1) = va1a; *(u64_t*)(As[0] + sw1 + 4) = va1b;
        va0a = ald(ap0 + 64); va0b = ald(ap0 + 68);
        va1a = ald(ap1 + 64); va1b = ald(ap1 + 68);
        __syncthreads();
        int p = 0;
        for (int k0 = 0; k0 < KE; k0 += 64) {
            int kn = k0 + 64;
            bf16x8 wn00, wn01, wn10, wn11;
            if (kn < KE) {
                *(u64_t*)(As[p ^ 1] + sw0) = va0a; *(u64_t*)(As[p ^ 1] + sw0 + 4) = va0b;
                *(u64_t*)(As[p ^ 1] + sw1) = va1a; *(u64_t*)(As[p ^ 1] + sw1 + 4) = va1b;
                if (kn + 64 < KE) {
                    va0a = ald(ap0 + kn + 64); va0b = ald(ap0 + kn + 68);
                    va1a = ald(ap1 + kn + 64); va1b = ald(ap1 + kn + 68);
                }
                wn00 = *(const bf16x8*)(wb0 + kn);
                wn01 = *(const bf16x8*)(wb1 + kn);
                wn10 = *(const bf16x8*)(wb0 + kn + 32);
                wn11 = *(const bf16x8*)(wb1 + kn + 32);
            }
            const ushort_t* Ab = As[p];
#pragma unroll
            for (int i = 0; i < 4; ++i) {
                int row = (i << 4) + r16;
                int xr = (row & 7) << 3;
                bf16x8 af0 = *(const bf16x8*)(Ab + (row << 6) + (q8 ^ xr));
                bf16x8 af1 = *(const bf16x8*)(Ab + (row << 6) + ((q8 + 32) ^ xr));
                acc[i][0] = MFMA16(af0, wf00, acc[i][0]);
                acc[i][1] = MFMA16(af0, wf01, acc[i][1]);
                acc[i][0] = MFMA16(af1, wf10, acc[i][0]);
                acc[i][1] = MFMA16(af1, wf11, acc[i][1]);
            }
            if (kn < KE) { wf00 = wn00; wf01 = wn01; wf10 = wn10; wf11 = wn11; }
            LGKM_BARRIER();
            p ^= 1;
        }
#pragma unroll
        for (int i = 0; i < 4; ++i)
#pragma unroll
            for (int j2 = 0; j2 < 2; ++j2)
#pragma unroll
                for (int r = 0; r < 4; ++r)
                    gbuf[g][(i * 16 + q * 4 + r) * 33 + j2 * 16 + r16] = acc[i][j2][r];
        __syncthreads();
        int sel = (len1 == s);
        const float* g0 = &gbuf[0][m * 33 + jc0];
        const float* g1 = &gbuf[1][m * 33 + jc0];
        const float* g2 = &gbuf[2][m * 33 + jc0];
        const float* g3 = &gbuf[3][m * 33 + jc0];
        union { ushort_t s8[8]; u64_t u[2]; } hb;
#pragma unroll
        for (int u = 0; u < 8; ++u) {
            float rr = sigm(g0[u] + bir[u] + bhr[u]);
            float zz = sigm(g1[u] + biz[u] + bhz[u]);
            float hn = g2[u] + bhn[u];
            float inn = g3[u] + bin[u];
            float nn = tanhf(inn + rr * hn);
            float h2 = (1.f - zz) * nn + zz * hreg[u];
            hreg[u] = h2;
            hb.s8[u] = f2bf(h2);
        }
        {
            ushort_t* dst = Aout + (size_t)bgl * KE + gj;
            ast(dst, hb.u[0]); ast(dst + 4, hb.u[1]);
        }
        if (sel) {
            size_t hi = (size_t)bgl * 1024 + gj;
            union { float f[8]; u64_t u[4]; } cf;
#pragma unroll
            for (int u = 0; u < 8; ++u) cf.f[u] = hreg[u];
#pragma unroll
            for (int w = 0; w < 4; ++w) ast(ctx_f + hi + w * 2, cf.u[w]);
            ast(ctx_b + hi, hb.u[0]); ast(ctx_b + hi + 4, hb.u[1]);
        }
        if (blockIdx.x == 0 && s + 1 < SS) {
            int rr2 = tid >> 2, c0 = (tid & 3) << 5;
#pragma unroll
            for (int cc = 0; cc < 32; cc += 8) {
                union { int4 v4; u64_t u[2]; } eu;
                eu.v4 = *(const int4*)(emb_pad + ((size_t)(s + 1) * BB + m0 + rr2) * 128 + c0 + cc);
                ushort_t* dst = Aout + (size_t)(m0 + rr2) * KE + 1024 + c0 + cc;
                ast(dst, eu.u[0]); ast(dst + 4, eu.u[1]);
            }
        }
        if (s + 1 < SS) gridbar(bar, (s + 1) * GRIDN);
    }
}

// Fill A_dec ctx columns for all 19 steps (decoder h-init comes from ctx_f/ctx_b)
__global__ void fill_ctx(const ushort_t* __restrict__ ctx_b, ushort_t* __restrict__ A_dec) {
    int idx = blockIdx.x * 256 + threadIdx.x;  // 19*256*1024
    int t = idx >> 18;
    int r = idx & 262143;
    int b = r >> 10;
    int k = r & 1023;
    A_dec[((size_t)(t * BB + b)) * KE + 128 + k] = ctx_b[r];
}

// ---------------------------------------------------------------------------
// 128x128 MFMA GEMM, ping-pong LDS + lgkm-only barrier + XOR swizzle.
// ---------------------------------------------------------------------------
template <typename OutT>
__global__ __launch_bounds__(256) void gemm128(const ushort_t* __restrict__ A,
                                               const ushort_t* __restrict__ W,
                                               OutT* __restrict__ C,
                                               int K, int lda, int ldw, int ldc) {
    __shared__ ushort_t As[2][128 * 32];
    __shared__ ushort_t Bs[2][128 * 32];
    int tid = threadIdx.x;
    int lane = tid & 63, wave = tid >> 6;
    int m0 = blockIdx.y << 7, n0 = blockIdx.x << 7;
    int row0 = tid >> 2, kc0 = (tid & 3) << 3;
    const ushort_t* a0p = A + (size_t)(m0 + row0) * lda + kc0;
    const ushort_t* a1p = A + (size_t)(m0 + row0 + 64) * lda + kc0;
    const ushort_t* w0p = W + (size_t)(n0 + row0) * ldw + kc0;
    const ushort_t* w1p = W + (size_t)(n0 + row0 + 64) * ldw + kc0;
    int mq = (wave >> 1) << 6, nq = (wave & 1) << 6;
    int r16 = lane & 15, q8 = (lane >> 4) << 3;
    const int sx = ((row0 >> 1) & 3) << 3;
    const int sw0 = (row0 << 5) + (kc0 ^ sx);
    const int sw1 = ((row0 + 64) << 5) + (kc0 ^ sx);
    f32x4 zero4 = {0.f, 0.f, 0.f, 0.f};
    f32x4 acc[4][4];
#pragma unroll
    for (int i = 0; i < 4; ++i)
#pragma unroll
        for (int j = 0; j < 4; ++j) acc[i][j] = zero4;
    int4 va0 = *(const int4*)(a0p);
    int4 va1 = *(const int4*)(a1p);
    int4 vb0 = *(const int4*)(w0p);
    int4 vb1 = *(const int4*)(w1p);
    *(int4*)(As[0] + sw0) = va0;
    *(int4*)(As[0] + sw1) = va1;
    *(int4*)(Bs[0] + sw0) = vb0;
    *(int4*)(Bs[0] + sw1) = vb1;
    va0 = *(const int4*)(a0p + 32);
    va1 = *(const int4*)(a1p + 32);
    vb0 = *(const int4*)(w0p + 32);
    vb1 = *(const int4*)(w1p + 32);
    __syncthreads();
    int p = 0;
    for (int k0 = 0; k0 < K; k0 += 32) {
        int kn = k0 + 32;
        if (kn < K) {
            *(int4*)(As[p ^ 1] + sw0) = va0;
            *(int4*)(As[p ^ 1] + sw1) = va1;
            *(int4*)(Bs[p ^ 1] + sw0) = vb0;
            *(int4*)(Bs[p ^ 1] + sw1) = vb1;
            if (kn + 32 < K) {
                va0 = *(const int4*)(a0p + kn + 32);
                va1 = *(const int4*)(a1p + kn + 32);
                vb0 = *(const int4*)(w0p + kn + 32);
                vb1 = *(const int4*)(w1p + kn + 32);
            }
        }
        bf16x8 af[4], bfv[4];
#pragma unroll
        for (int i = 0; i < 4; ++i) {
            int ar = mq + i * 16 + r16;
            af[i] = *(const bf16x8*)(As[p] + (ar << 5) + (q8 ^ ((((ar) >> 1) & 3) << 3)));
        }
#pragma unroll
        for (int j = 0; j < 4; ++j) {
            int br = nq + j * 16 + r16;
            bfv[j] = *(const bf16x8*)(Bs[p] + (br << 5) + (q8 ^ ((((br) >> 1) & 3) << 3)));
        }
#pragma unroll
        for (int i = 0; i < 4; ++i)
#pragma unroll
            for (int j = 0; j < 4; ++j) acc[i][j] = MFMA16(af[i], bfv[j], acc[i][j]);
        LGKM_BARRIER();
        p ^= 1;
    }
    int rbase = (lane >> 4) << 2;
#pragma unroll
    for (int i = 0; i < 4; ++i)
#pragma unroll
        for (int j = 0; j < 4; ++j)
#pragma unroll
            for (int r = 0; r < 4; ++r)
                storeC(&C[(size_t)(m0 + mq + i * 16 + rbase + r) * ldc + (n0 + nq + j * 16 + r16)],
                       acc[i][j][r]);
}

// ---------------------------------------------------------------------------
// PERSISTENT decoder: all 19 GRU steps in one launch, same barrier scheme.
// ---------------------------------------------------------------------------
__global__ __launch_bounds__(256) void dec_all(
    const ushort_t* __restrict__ ctx_b, ushort_t* __restrict__ H_all,
    const ushort_t* __restrict__ W, const ushort_t* __restrict__ gi_all,
    const float* __restrict__ bi, const float* __restrict__ bh,
    const float* __restrict__ ctx_f, int* __restrict__ bar) {
    __shared__ ushort_t As[2][64 * 64];
    __shared__ float gbuf[3][64 * 33];
    int tid = threadIdx.x;
    int lane = tid & 63, g = tid >> 6;
    int j0 = blockIdx.x << 5, m0 = blockIdx.y << 6;
    int r16 = lane & 15, q = lane >> 4, q8 = q << 3;
    int srow = tid >> 3, skc = (tid & 7) << 3;
    const size_t offA = (size_t)(m0 + srow) * HH + skc;
    const int sx = (srow & 7) << 3;
    const int sw0 = (srow << 6) + (skc ^ sx);
    const int sw1 = ((srow + 32) << 6) + (skc ^ sx);
    const ushort_t* wb0 = W + (size_t)(g * 1024 + j0 + r16) * HH + q8;
    const ushort_t* wb1 = wb0 + (size_t)16 * HH;
    int m = tid & 63, jc0 = (tid >> 6) << 3;
    int bgl = m0 + m, gj = j0 + jc0;
    float bir[8], bhr[8], biz[8], bhz[8], bhn[8], bin[8];
#pragma unroll
    for (int u = 0; u < 8; ++u) {
        int jg = gj + u;
        bir[u] = bi[jg];        bhr[u] = bh[jg];
        biz[u] = bi[1024 + jg]; bhz[u] = bh[1024 + jg];
        bhn[u] = bh[2048 + jg]; bin[u] = bi[2048 + jg];
    }
    float hreg[8];
#pragma unroll
    for (int u = 0; u < 8; ++u) hreg[u] = ctx_f[(size_t)bgl * HH + gj + u];

    for (int t = 0; t < TT - 1; ++t) {
        const ushort_t* Ain = t ? (H_all + (size_t)(t - 1) * BB * HH) : ctx_b;
        ushort_t* Aout = H_all + (size_t)t * BB * HH;
        const ushort_t* ap0 = Ain + offA;
        const ushort_t* ap1 = ap0 + (size_t)32 * HH;
        const ushort_t* gip = gi_all + (size_t)t * BB * G3 + (size_t)bgl * G3;
        f32x4 zero = {0.f, 0.f, 0.f, 0.f};
        f32x4 acc[4][2];
#pragma unroll
        for (int i = 0; i < 4; ++i) { acc[i][0] = zero; acc[i][1] = zero; }
        u64_t va0a = ald(ap0), va0b = ald(ap0 + 4);
        u64_t va1a = ald(ap1), va1b = ald(ap1 + 4);
        bf16x8 wf00 = {0, 0, 0, 0, 0, 0, 0, 0}, wf01 = wf00, wf10 = wf00, wf11 = wf00;
        if (g < 3) {
            wf00 = *(const bf16x8*)(wb0);
            wf01 = *(const bf16x8*)(wb1);
            wf10 = *(const bf16x8*)(wb0 + 32);
            wf11 = *(const bf16x8*)(wb1 + 32);
        }
        *(u64_t*)(As[0] + sw0) = va0a; *(u64_t*)(As[0] + sw0 + 4) = va0b;
        *(u64_t*)(As[0] + sw1) = va1a; *(u64_t*)(As[0] + sw1 + 4) = va1b;
        va0a = ald(ap0 + 64); va0b = ald(ap0 + 68);
        va1a = ald(ap1 + 64); va1b = ald(ap1 + 68);
        __syncthreads();
        int p = 0;
        for (int k0 = 0; k0 < HH; k0 += 64) {
            int kn = k0 + 64;
            bf16x8 wn00, wn01, wn10, wn11;
            if (kn < HH) {
                *(u64_t*)(As[p ^ 1] + sw0) = va0a; *(u64_t*)(As[p ^ 1] + sw0 + 4) = va0b;
                *(u64_t*)(As[p ^ 1] + sw1) = va1a; *(u64_t*)(As[p ^ 1] + sw1 + 4) = va1b;
                if (kn + 64 < HH) {
                    va0a = ald(ap0 + kn + 64); va0b = ald(ap0 + kn + 68);
                    va1a = ald(ap1 + kn + 64); va1b = ald(ap1 + kn + 68);
                }
                if (g < 3) {
                    wn00 = *(const bf16x8*)(wb0 + kn);
                    wn01 = *(const bf16x8*)(wb1 + kn);
                    wn10 = *(const bf16x8*)(wb0 + kn + 32);
                    wn11 = *(const bf16x8*)(wb1 + kn + 32);
                }
            }
            if (g < 3) {
                const ushort_t* Ab = As[p];
#pragma unroll
                for (int i = 0; i < 4; ++i) {
                    int row = (i << 4) + r16;
                    int xr = (row & 7) << 3;
                    bf16x8 af0 = *(const bf16x8*)(Ab + (row << 6) + (q8 ^ xr));
                    bf16x8 af1 = *(const bf16x8*)(Ab + (row << 6) + ((q8 + 32) ^ xr));
                    acc[i][0] = MFMA16(af0, wf00, acc[i][0]);
                    acc[i][1] = MFMA16(af0, wf01, acc[i][1]);
                    acc[i][0] = MFMA16(af1, wf10, acc[i][0]);
                    acc[i][1] = MFMA16(af1, wf11, acc[i][1]);
                }
                if (kn < HH) { wf00 = wn00; wf01 = wn01; wf10 = wn10; wf11 = wn11; }
            }
            LGKM_BARRIER();
            p ^= 1;
        }
        if (g < 3) {
#pragma unroll
            for (int i = 0; i < 4; ++i)
#pragma unroll
                for (int j2 = 0; j2 < 2; ++j2)
#pragma unroll
                    for (int r = 0; r < 4; ++r)
                        gbuf[g][(i * 16 + q * 4 + r) * 33 + j2 * 16 + r16] = acc[i][j2][r];
        }
        __syncthreads();
        ushort_t gr[8], gz[8], gn[8];
        *(int4*)gr = *(const int4*)(gip + gj);
        *(int4*)gz = *(const int4*)(gip + 1024 + gj);
        *(int4*)gn = *(const int4*)(gip + 2048 + gj);
        const float* g0 = &gbuf[0][m * 33 + jc0];
        const float* g1 = &gbuf[1][m * 33 + jc0];
        const float* g2 = &gbuf[2][m * 33 + jc0];
        union { ushort_t s8[8]; u64_t u[2]; } hb;
#pragma unroll
        for (int u = 0; u < 8; ++u) {
            float rr = sigm(g0[u] + bhr[u] + bf2f(gr[u]) + bir[u]);
            float zz = sigm(g1[u] + bhz[u] + bf2f(gz[u]) + biz[u]);
            float hn = g2[u] + bhn[u];
            float inn = bf2f(gn[u]) + bin[u];
            float nn = tanhf(inn + rr * hn);
            float h2 = (1.f - zz) * nn + zz * hreg[u];
            hreg[u] = h2;
            hb.s8[u] = f2bf(h2);
        }
        {
            ushort_t* dst = Aout + (size_t)bgl * 1024 + gj;
            ast(dst, hb.u[0]); ast(dst + 4, hb.u[1]);
        }
        if (t + 1 < TT - 1) gridbar(bar + 16, (t + 1) * GRIDN);
    }
}

// ---------------------------------------------------------------------------
// BATCHED fused logits GEMM + CE partials, XCD-chunked (each XCD owns 5
// m-tiles; W panel fetched once per XCD, reused 5x from L2).
// ---------------------------------------------------------------------------
__global__ __launch_bounds__(256) void logits_ce(
    const ushort_t* __restrict__ A, const ushort_t* __restrict__ Wf,
    const float* __restrict__ bfc, const int* __restrict__ targets,
    float* __restrict__ part_max, float* __restrict__ part_sum,
    float* __restrict__ xt) {
    int bid = blockIdx.x;
    int xcd = bid & 7;
    int slot = bid >> 3;
    int n_t = slot / 5;
    int m_t = xcd * 5 + (slot - n_t * 5);
    if (m_t >= (TT - 1) * BB / 128) return;
    __shared__ ushort_t As[2][128 * 32];
    __shared__ ushort_t Bs[2][128 * 32];
    __shared__ float wm[128][2], ws2[128][2];
    int tid = threadIdx.x;
    int lane = tid & 63, wave = tid >> 6;
    int m0 = m_t << 7, n0 = n_t << 7;
    int row0 = tid >> 2, kc0 = (tid & 3) << 3;
    const ushort_t* a0p = A + (size_t)(m0 + row0) * HH + kc0;
    const ushort_t* a1p = A + (size_t)(m0 + row0 + 64) * HH + kc0;
    const ushort_t* w0p = Wf + (size_t)(n0 + row0) * HH + kc0;
    const ushort_t* w1p = Wf + (size_t)(n0 + row0 + 64) * HH + kc0;
    int mq = (wave >> 1) << 6, nq = (wave & 1) << 6;
    int r16 = lane & 15, q = lane >> 4, q8 = q << 3;
    const int sx = ((row0 >> 1) & 3) << 3;
    const int sw0 = (row0 << 5) + (kc0 ^ sx);
    const int sw1 = ((row0 + 64) << 5) + (kc0 ^ sx);
    f32x4 zero4 = {0.f, 0.f, 0.f, 0.f};
    f32x4 acc[4][4];
#pragma unroll
    for (int i = 0; i < 4; ++i)
#pragma unroll
        for (int j = 0; j < 4; ++j) acc[i][j] = zero4;
    int4 va0 = *(const int4*)(a0p);
    int4 va1 = *(const int4*)(a1p);
    int4 vb0 = *(const int4*)(w0p);
    int4 vb1 = *(const int4*)(w1p);
    *(int4*)(As[0] + sw0) = va0;
    *(int4*)(As[0] + sw1) = va1;
    *(int4*)(Bs[0] + sw0) = vb0;
    *(int4*)(Bs[0] + sw1) = vb1;
    va0 = *(const int4*)(a0p + 32);
    va1 = *(const int4*)(a1p + 32);
    vb0 = *(const int4*)(w0p + 32);
    vb1 = *(const int4*)(w1p + 32);
    __syncthreads();
    int p = 0;
    for (int k0 = 0; k0 < HH; k0 += 32) {
        int kn = k0 + 32;
        if (kn < HH) {
            *(int4*)(As[p ^ 1] + sw0) = va0;
            *(int4*)(As[p ^ 1] + sw1) = va1;
            *(int4*)(Bs[p ^ 1] + sw0) = vb0;
            *(int4*)(Bs[p ^ 1] + sw1) = vb1;
            if (kn + 32 < HH) {
                va0 = *(const int4*)(a0p + kn + 32);
                va1 = *(const int4*)(a1p + kn + 32);
                vb0 = *(const int4*)(w0p + kn + 32);
                vb1 = *(const int4*)(w1p + kn + 32);
            }
        }
        bf16x8 af[4], bfv[4];
#pragma unroll
        for (int i = 0; i < 4; ++i) {
            int ar = mq + i * 16 + r16;
            af[i] = *(const bf16x8*)(As[p] + (ar << 5) + (q8 ^ ((((ar) >> 1) & 3) << 3)));
        }
#pragma unroll
        for (int j = 0; j < 4; ++j) {
            int br = nq + j * 16 + r16;
            bfv[j] = *(const bf16x8*)(Bs[p] + (br << 5) + (q8 ^ ((((br) >> 1) & 3) << 3)));
        }
#pragma unroll
        for (int i = 0; i < 4; ++i)
#pragma unroll
            for (int j = 0; j < 4; ++j) acc[i][j] = MFMA16(af[i], bfv[j], acc[i][j]);
        LGKM_BARRIER();
        p ^= 1;
    }
    float bias[4];
#pragma unroll
    for (int j2 = 0; j2 < 4; ++j2) bias[j2] = bfc[n0 + nq + j2 * 16 + r16];
    int nw = wave & 1;
#pragma unroll
    for (int i = 0; i < 4; ++i) {
#pragma unroll
        for (int r = 0; r < 4; ++r) {
            int rloc = mq + i * 16 + q * 4 + r;
            int brow = m0 + rloc;
            int y = targets[(brow & 255) * TT + (brow >> 8) + 1];
            float v[4];
            float mx = -3.0e38f;
#pragma unroll
            for (int j2 = 0; j2 < 4; ++j2) {
                v[j2] = acc[i][j2][r] + bias[j2];
                if (n0 + nq + j2 * 16 + r16 == y) xt[brow] = v[j2];
                mx = fmaxf(mx, v[j2]);
            }
#pragma unroll
            for (int d = 1; d < 16; d <<= 1) mx = fmaxf(mx, __shfl_xor(mx, d, 64));
            float se = 0.f;
#pragma unroll
            for (int j2 = 0; j2 < 4; ++j2) se += expf(v[j2] - mx);
#pragma unroll
            for (int d = 1; d < 16; d <<= 1) se += __shfl_xor(se, d, 64);
            if (r16 == 0) { wm[rloc][nw] = mx; ws2[rloc][nw] = se; }
        }
    }
    __syncthreads();
    if (tid < 128) {
        float m0v = wm[tid][0], m1v = wm[tid][1];
        float M = fmaxf(m0v, m1v);
        float S = ws2[tid][0] * expf(m0v - M) + ws2[tid][1] * expf(m1v - M);
        int brow = m0 + tid;
        part_max[(size_t)brow * 256 + n_t] = M;
        part_sum[(size_t)brow * 256 + n_t] = S;
    }
}

// Merge 250 per-row partials -> CE for all 4864 rows; atomicAdd ce_sum[t]
__global__ void ce_merge(const float* __restrict__ pm, const float* __restrict__ ps,
                         const float* __restrict__ xt, float* __restrict__ ce_sum) {
    int row = blockIdx.x * 4 + (threadIdx.x >> 6);
    int lane = threadIdx.x & 63;
    const float* pmr = pm + (size_t)row * 256;
    const float* psr = ps + (size_t)row * 256;
    float lm[4];
    int cnt = 0;
    float mx = -3.0e38f;
    for (int i = lane; i < 250; i += 64) { float v = pmr[i]; lm[cnt++] = v; mx = fmaxf(mx, v); }
    for (int d = 1; d < 64; d <<= 1) mx = fmaxf(mx, __shfl_xor(mx, d, 64));
    float s = 0.f;
    cnt = 0;
    for (int i = lane; i < 250; i += 64) { s += psr[i] * expf(lm[cnt++] - mx); }
    for (int d = 1; d < 64; d <<= 1) s += __shfl_xor(s, d, 64);
    if (lane == 0) atomicAdd(&ce_sum[row >> 8], mx + logf(s) - xt[row]);
}

// loss = (1/T) * sum_t (ce_sum[t]/B) * (mask_sum[t]/B)
__global__ void finalize(const float* __restrict__ ce_sum, const int* __restrict__ targets,
                         float* __restrict__ out) {
    int lane = threadIdx.x;
    float term = 0.f;
    if (lane < TT - 1) {
        int msum = 0;
        for (int b = 0; b < BB; ++b) msum += (targets[b * TT + lane + 1] >= 1) ? 1 : 0;
        term = (ce_sum[lane] * (1.f / BB)) * ((float)msum * (1.f / BB));
    }
    for (int off = 32; off > 0; off >>= 1) term += __shfl_down(term, off, 64);
    if (lane == 0) out[0] = term * (1.f / TT);
}

extern "C" void kernel_launch(void* const* d_in, const int* in_sizes, int n_in,
                              void* d_out, int out_size, void* d_ws, size_t ws_size,
                              hipStream_t stream) {
    const int* inputs = (const int*)d_in[0];
    const int* targets = (const int*)d_in[1];
    const int* lengths = (const int*)d_in[2];
    const float* h0 = (const float*)d_in[3];
    const float* E_enc = (const float*)d_in[4];
    const float* E_dec = (const float*)d_in[5];
    const float* W_ih_e = (const float*)d_in[6];
    const float* W_hh_e = (const float*)d_in[7];
    const float* b_ih_e = (const float*)d_in[8];
    const float* b_hh_e = (const float*)d_in[9];
    const float* W_ih_d = (const float*)d_in[10];
    const float* W_hh_d = (const float*)d_in[11];
    const float* b_ih_d = (const float*)d_in[12];
    const float* b_hh_d = (const float*)d_in[13];
    const float* W_fc = (const float*)d_in[14];
    const float* b_fc = (const float*)d_in[15];

    char* ws = (char*)d_ws;
    size_t off = 0;
    auto alloc = [&](size_t bytes) -> char* {
        char* p = ws + off;
        off += (bytes + 255) & ~(size_t)255;
        return p;
    };
    const int MROWS = (TT - 1) * BB;  // 4864
    ushort_t* W_enc_big = (ushort_t*)alloc((size_t)G4 * KE * 2);
    ushort_t* W_dec_pad = (ushort_t*)alloc((size_t)G3 * KE * 2);
    ushort_t* W_hhd_b = (ushort_t*)alloc((size_t)G3 * HH * 2);
    ushort_t* W_fc_b = (ushort_t*)alloc((size_t)VV * HH * 2);
    ushort_t* emb_pad = (ushort_t*)alloc((size_t)SS * BB * 128 * 2);
    ushort_t* A_enc0 = (ushort_t*)alloc((size_t)BB * KE * 2);
    ushort_t* A_enc1 = (ushort_t*)alloc((size_t)BB * KE * 2);
    ushort_t* A_dec = (ushort_t*)alloc((size_t)MROWS * KE * 2);
    ushort_t* gi_dec = (ushort_t*)alloc((size_t)MROWS * G3 * 2);
    ushort_t* H_all = (ushort_t*)alloc((size_t)MROWS * HH * 2);
    float* ctx_f = (float*)alloc((size_t)BB * HH * 4);
    ushort_t* ctx_b = (ushort_t*)alloc((size_t)BB * HH * 2);
    float* part_max = (float*)alloc((size_t)MROWS * 256 * 4);
    float* part_sum = (float*)alloc((size_t)MROWS * 256 * 4);
    float* xt = (float*)alloc((size_t)MROWS * 4);
    float* ce_sum = (float*)alloc(64 * 4);
    int* bar = (int*)alloc(64 * 4);

    // ---- prep ----
    prep_w<<<(G4 + G3) * (KE / 8) / 256, 256, 0, stream>>>(W_hh_e, W_ih_e, W_ih_d,
                                                           W_enc_big, W_dec_pad);
    conv_w<<<(G3 * HH + VV * HH) / 8 / 256, 256, 0, stream>>>(W_hh_d, W_fc, W_hhd_b, W_fc_b);
    {
        int nx = SS * BB * 128 + BB * KE + (TT - 1) * BB * 128 + 96;
        prep_x<<<(nx + 255) / 256, 256, 0, stream>>>(inputs, targets, h0, E_enc, E_dec,
                                                     emb_pad, A_enc0, A_dec, ce_sum, bar);
    }

    // ---- encoder: ONE persistent launch, 64 steps, fence-free barriers ----
    enc_all<<<dim3(32, 4), 256, 0, stream>>>(A_enc0, A_enc1, W_enc_big, b_ih_e, b_hh_e,
                                             h0, emb_pad, lengths, ctx_f, ctx_b, bar);

    // ---- decoder input-side gates: one big GEMM ----
    fill_ctx<<<((TT - 1) * BB * HH) / 256, 256, 0, stream>>>(ctx_b, A_dec);
    gemm128<ushort_t><<<dim3(G3 / 128, MROWS / 128), 256, 0, stream>>>(
        A_dec, W_dec_pad, gi_dec, KE, KE, KE, G3);

    // ---- decoder: ONE persistent launch, 19 steps writing H_all ----
    dec_all<<<dim3(32, 4), 256, 0, stream>>>(ctx_b, H_all, W_hhd_b, gi_dec,
                                             b_ih_d, b_hh_d, ctx_f, bar);

    // ---- ONE batched logits+CE over all 19 steps (XCD-chunked), one merge ----
    logits_ce<<<10000, 256, 0, stream>>>(H_all, W_fc_b, b_fc, targets,
                                         part_max, part_sum, xt);
    ce_merge<<<MROWS / 4, 256, 0, stream>>>(part_max, part_sum, xt, ce_sum);

    finalize<<<1, 64, 0, stream>>>(ce_sum, targets, (float*)d_out);
}

// Round 4
// 1800.133 us; speedup vs baseline: 1.8531x; 1.4498x over previous
//
#include <hip/hip_runtime.h>
#include <stdint.h>

#define BB 256
#define SS 64
#define TT 20
#define HH 1024
#define EE 100
#define G3 3072
#define G4 4096
#define KE 1152     // 1024 + 128 (E padded to 128)
#define VV 32000

typedef unsigned short ushort_t;
typedef unsigned long long u64_t;
typedef short bf16x8 __attribute__((ext_vector_type(8)));
typedef float f32x4 __attribute__((ext_vector_type(4)));

#define DEV static __device__ __forceinline__

DEV float bf2f(ushort_t h) {
    union { uint32_t u; float f; } c; c.u = ((uint32_t)h) << 16; return c.f;
}
DEV ushort_t f2bf(float x) {
    union { float f; uint32_t u; } c; c.f = x;
    uint32_t r = (c.u + 0x7fffu + ((c.u >> 16) & 1u)) >> 16;
    return (ushort_t)r;
}
DEV float sigm(float x) { return 1.f / (1.f + expf(-x)); }

DEV void storeC(float* p, float v) { *p = v; }
DEV void storeC(ushort_t* p, float v) { *p = f2bf(v); }

// Relaxed agent-scope (sc1, LLC-coherent) 8B accesses for cross-XCD data.
DEV u64_t ald(const void* p) {
    return __hip_atomic_load((const u64_t*)p, __ATOMIC_RELAXED, __HIP_MEMORY_SCOPE_AGENT);
}
DEV void ast(void* p, u64_t v) {
    __hip_atomic_store((u64_t*)p, v, __ATOMIC_RELAXED, __HIP_MEMORY_SCOPE_AGENT);
}

#define MFMA16(a, b, c) __builtin_amdgcn_mfma_f32_16x16x32_bf16(a, b, c, 0, 0, 0)

// One barrier per K-chunk: drain LDS ops only; global loads stay in flight.
#define LGKM_BARRIER()                                         \
    do {                                                       \
        asm volatile("s_waitcnt lgkmcnt(0)" ::: "memory");     \
        __builtin_amdgcn_s_barrier();                          \
    } while (0)

// Per-m-group barrier (32 arrivals). All relaxed: __syncthreads' vmcnt(0)
// drain already makes this block's sc1 stores LLC-visible before arrival.
DEV void groupbar(int* ctr, int target) {
    __syncthreads();
    if (threadIdx.x == 0) {
        __hip_atomic_fetch_add(ctr, 1, __ATOMIC_RELAXED, __HIP_MEMORY_SCOPE_AGENT);
        while (__hip_atomic_load(ctr, __ATOMIC_RELAXED, __HIP_MEMORY_SCOPE_AGENT) < target)
            __builtin_amdgcn_s_sleep(2);
    }
    __syncthreads();
    asm volatile("" ::: "memory");
}

// ---------------------------------------------------------------------------
// prep_w: build bf16 W_enc_big [4096][1152], W_dec_pad [3072][1152] from fp32.
// ---------------------------------------------------------------------------
__global__ void prep_w(const float* __restrict__ W_hh_e, const float* __restrict__ W_ih_e,
                       const float* __restrict__ W_ih_d,
                       ushort_t* __restrict__ W_enc_big, ushort_t* __restrict__ W_dec_pad) {
    int idx = blockIdx.x * 256 + threadIdx.x;  // (G4+G3) * (KE/8)
    int n = idx / 144, kc = (idx - n * 144) * 8;
    ushort_t o[8];
    if (n < G4) {
        if (kc < HH) {
            if (n < G3) {
#pragma unroll
                for (int u = 0; u < 8; ++u) o[u] = f2bf(W_hh_e[(size_t)n * HH + kc + u]);
            } else {
#pragma unroll
                for (int u = 0; u < 8; ++u) o[u] = 0;
            }
        } else {
            int kk = kc - HH;
#pragma unroll
            for (int u = 0; u < 8; ++u) {
                int k2 = kk + u;
                ushort_t v = 0;
                if (k2 < EE) {
                    if (n < 2048) v = f2bf(W_ih_e[(size_t)n * EE + k2]);
                    else if (n >= G3) v = f2bf(W_ih_e[(size_t)(n - HH) * EE + k2]);
                }
                o[u] = v;
            }
        }
        *(int4*)(W_enc_big + (size_t)n * KE + kc) = *(int4*)o;
    } else {
        int nd = n - G4;
        if (kc < 128) {
#pragma unroll
            for (int u = 0; u < 8; ++u) {
                int k2 = kc + u;
                o[u] = (k2 < EE) ? f2bf(W_ih_d[(size_t)nd * 1124 + k2]) : (ushort_t)0;
            }
        } else {
#pragma unroll
            for (int u = 0; u < 8; ++u) o[u] = f2bf(W_ih_d[(size_t)nd * 1124 + EE + (kc - 128) + u]);
        }
        *(int4*)(W_dec_pad + (size_t)nd * KE + kc) = *(int4*)o;
    }
}

__global__ void conv_w(const float* __restrict__ W_hh_d, const float* __restrict__ W_fc,
                       ushort_t* __restrict__ W_hhd_b, ushort_t* __restrict__ W_fc_b) {
    int idx = blockIdx.x * 256 + threadIdx.x;
    const int N1 = G3 * HH / 8;
    const float* src;
    ushort_t* dst;
    size_t e;
    if (idx < N1) { e = (size_t)idx * 8; src = W_hh_d; dst = W_hhd_b; }
    else { e = (size_t)(idx - N1) * 8; src = W_fc; dst = W_fc_b; }
    float4 a = *(const float4*)(src + e);
    float4 b = *(const float4*)(src + e + 4);
    ushort_t o[8] = {f2bf(a.x), f2bf(a.y), f2bf(a.z), f2bf(a.w),
                     f2bf(b.x), f2bf(b.y), f2bf(b.z), f2bf(b.w)};
    *(int4*)(dst + e) = *(int4*)o;
}

// ---------------------------------------------------------------------------
// prep_x: emb_pad, A_enc0 = [h0 | emb_0], A_dec demb part, ce_sum = 0, bar = 0
// ---------------------------------------------------------------------------
__global__ void prep_x(const int* __restrict__ inputs, const int* __restrict__ targets,
                       const float* __restrict__ h0, const float* __restrict__ E_enc,
                       const float* __restrict__ E_dec,
                       ushort_t* __restrict__ emb_pad, ushort_t* __restrict__ A_enc,
                       ushort_t* __restrict__ A_dec,
                       float* __restrict__ ce_sum, int* __restrict__ bar) {
    int idx = blockIdx.x * 256 + threadIdx.x;
    const int R0 = SS * BB * 128;
    const int R1 = R0 + BB * KE;
    const int R2 = R1 + (TT - 1) * BB * 128;
    const int R3 = R2 + 32 + 1024;
    if (idx < R0) {
        int s = idx >> 15;
        int r = idx & 32767;
        int b = r >> 7, k = r & 127;
        emb_pad[idx] = (k < EE) ? f2bf(E_enc[(size_t)inputs[b * SS + s] * EE + k]) : (ushort_t)0;
    } else if (idx < R1) {
        int i = idx - R0;
        int b = i / KE, c = i - b * KE;
        ushort_t v;
        if (c < HH) v = f2bf(h0[b * HH + c]);
        else { int kk = c - HH; v = (kk < EE) ? f2bf(E_enc[(size_t)inputs[b * SS] * EE + kk]) : (ushort_t)0; }
        A_enc[i] = v;
    } else if (idx < R2) {
        int i = idx - R1;
        int t = i >> 15;
        int r = i & 32767;
        int b = r >> 7, k = r & 127;
        int tok = (t == 0) ? 1 : targets[b * TT + t];
        A_dec[((size_t)(t * BB + b)) * KE + k] = (k < EE) ? f2bf(E_dec[(size_t)tok * EE + k]) : (ushort_t)0;
    } else if (idx < R2 + 32) {
        ce_sum[idx - R2] = 0.f;
    } else if (idx < R3) {
        bar[idx - R2 - 32] = 0;
    }
}

// ---------------------------------------------------------------------------
// PERSISTENT encoder v2: 256 blocks (all CUs), 32-row m-tiles, XCD-aware
// (jb,mg) decomposition so each XCD's W slice (1.2 MB) stays L2-resident.
// Distance-2 register prefetch of sc1 A loads; per-m-group barriers.
//   bid -> xcd = bid&7, jb = xcd*4 + (bid>>3)&3 (j-cols 32*jb), mg = bid>>5.
// ---------------------------------------------------------------------------
__global__ __launch_bounds__(256) void enc_all(
    ushort_t* __restrict__ A0, ushort_t* __restrict__ A1,
    const ushort_t* __restrict__ W, const float* __restrict__ bi,
    const float* __restrict__ bh, const float* __restrict__ h0,
    const ushort_t* __restrict__ emb_pad, const int* __restrict__ lengths,
    float* __restrict__ ctx_f, ushort_t* __restrict__ ctx_b, int* __restrict__ bar) {
    __shared__ __align__(16) ushort_t As[2][32 * 64];
    __shared__ float gbuf[4][32 * 33];
    int tid = threadIdx.x;
    int bid = blockIdx.x;
    int lane = tid & 63, g = tid >> 6;
    int jb = (bid & 7) * 4 + ((bid >> 3) & 3);   // 0..31
    int mg = bid >> 5;                            // 0..7
    int j0 = jb << 5, m0 = mg << 5;
    int* barp = bar + mg * 64;
    int r16 = lane & 15, q = lane >> 4, q8 = q << 3;
    int srow = tid >> 3, skc = (tid & 7) << 3;
    const size_t offA = (size_t)(m0 + srow) * KE + skc;
    const int sx = (srow & 7) << 3;
    const int sw = (srow << 6) + (skc ^ sx);
    const ushort_t* wb0 = W + (size_t)(g * 1024 + j0 + r16) * KE + q8;
    const ushort_t* wb1 = wb0 + (size_t)16 * KE;
    int m = tid & 31, jc0 = (tid >> 5) << 2;
    int bgl = m0 + m, gjj = j0 + jc0;
    int len1 = lengths[bgl] - 1;
    float bir[4], bhr[4], biz[4], bhz[4], bhn[4], bin[4];
#pragma unroll
    for (int u = 0; u < 4; ++u) {
        int jg = gjj + u;
        bir[u] = bi[jg];        bhr[u] = bh[jg];
        biz[u] = bi[1024 + jg]; bhz[u] = bh[1024 + jg];
        bhn[u] = bh[2048 + jg]; bin[u] = bi[2048 + jg];
    }
    float hreg[4];
#pragma unroll
    for (int u = 0; u < 4; ++u) hreg[u] = h0[(size_t)bgl * HH + gjj + u];

#pragma unroll 1
    for (int s = 0; s < SS; ++s) {
        const ushort_t* Ain = (s & 1) ? A1 : A0;
        ushort_t* Aout = (s & 1) ? A0 : A1;
        const ushort_t* ap = Ain + offA;
        f32x4 zero = {0.f, 0.f, 0.f, 0.f};
        f32x4 acc[2][2];
        acc[0][0] = zero; acc[0][1] = zero; acc[1][0] = zero; acc[1][1] = zero;
        // 3 chunk loads in flight (distance-2 pipeline)
        u64_t t0a = ald(ap), t0b = ald(ap + 4);
        u64_t b0a = ald(ap + 64), b0b = ald(ap + 68);
        u64_t b1a = ald(ap + 128), b1b = ald(ap + 132);
        bf16x8 wf00 = *(const bf16x8*)(wb0);
        bf16x8 wf01 = *(const bf16x8*)(wb1);
        bf16x8 wf10 = *(const bf16x8*)(wb0 + 32);
        bf16x8 wf11 = *(const bf16x8*)(wb1 + 32);
        { union { u64_t u[2]; int4 v; } st; st.u[0] = t0a; st.u[1] = t0b;
          *(int4*)(As[0] + sw) = st.v; }
        __syncthreads();
        const int NC = KE / 64;  // 18
#pragma unroll
        for (int c = 0; c < NC; ++c) {
            int kn = (c + 1) << 6;
            bf16x8 wn00, wn01, wn10, wn11;
            if (c + 1 < NC) {
                union { u64_t u[2]; int4 v; } st;
                if (c & 1) { st.u[0] = b1a; st.u[1] = b1b; }
                else       { st.u[0] = b0a; st.u[1] = b0b; }
                *(int4*)(As[(c + 1) & 1] + sw) = st.v;
                if (c + 3 < NC) {
                    int kf = (c + 3) << 6;
                    if (c & 1) { b1a = ald(ap + kf); b1b = ald(ap + kf + 4); }
                    else       { b0a = ald(ap + kf); b0b = ald(ap + kf + 4); }
                }
                wn00 = *(const bf16x8*)(wb0 + kn);
                wn01 = *(const bf16x8*)(wb1 + kn);
                wn10 = *(const bf16x8*)(wb0 + kn + 32);
                wn11 = *(const bf16x8*)(wb1 + kn + 32);
            }
            const ushort_t* Ab = As[c & 1];
#pragma unroll
            for (int i = 0; i < 2; ++i) {
                int row = (i << 4) + r16;
                int xr = (row & 7) << 3;
                bf16x8 af0 = *(const bf16x8*)(Ab + (row << 6) + (q8 ^ xr));
                bf16x8 af1 = *(const bf16x8*)(Ab + (row << 6) + ((q8 + 32) ^ xr));
                acc[i][0] = MFMA16(af0, wf00, acc[i][0]);
                acc[i][1] = MFMA16(af0, wf01, acc[i][1]);
                acc[i][0] = MFMA16(af1, wf10, acc[i][0]);
                acc[i][1] = MFMA16(af1, wf11, acc[i][1]);
            }
            if (c + 1 < NC) { wf00 = wn00; wf01 = wn01; wf10 = wn10; wf11 = wn11; }
            LGKM_BARRIER();
        }
#pragma unroll
        for (int i = 0; i < 2; ++i)
#pragma unroll
            for (int j2 = 0; j2 < 2; ++j2)
#pragma unroll
                for (int r = 0; r < 4; ++r)
                    gbuf[g][(i * 16 + q * 4 + r) * 33 + j2 * 16 + r16] = acc[i][j2][r];
        __syncthreads();
        int sel = (len1 == s);
        const float* gp0 = &gbuf[0][m * 33 + jc0];
        const float* gp1 = &gbuf[1][m * 33 + jc0];
        const float* gp2 = &gbuf[2][m * 33 + jc0];
        const float* gp3 = &gbuf[3][m * 33 + jc0];
        union { ushort_t s4[4]; u64_t u; } hb;
#pragma unroll
        for (int u = 0; u < 4; ++u) {
            float rr = sigm(gp0[u] + bir[u] + bhr[u]);
            float zz = sigm(gp1[u] + biz[u] + bhz[u]);
            float hn = gp2[u] + bhn[u];
            float inn = gp3[u] + bin[u];
            float nn = tanhf(inn + rr * hn);
            float h2 = (1.f - zz) * nn + zz * hreg[u];
            hreg[u] = h2;
            hb.s4[u] = f2bf(h2);
        }
        ast(Aout + (size_t)bgl * KE + gjj, hb.u);
        if (sel) {
            size_t hi = (size_t)bgl * 1024 + gjj;
            union { float f[2]; u64_t u; } c0, c1;
            c0.f[0] = hreg[0]; c0.f[1] = hreg[1];
            c1.f[0] = hreg[2]; c1.f[1] = hreg[3];
            ast(ctx_f + hi, c0.u); ast(ctx_f + hi + 2, c1.u);
            ast(ctx_b + hi, hb.u);
        }
        if (jb == 0 && s + 1 < SS) {
            int rr2 = tid >> 3, c0e = (tid & 7) << 4;
            const ushort_t* esrc = emb_pad + ((size_t)(s + 1) * BB + m0 + rr2) * 128 + c0e;
            union { int4 v; u64_t u[2]; } e0, e1;
            e0.v = *(const int4*)esrc;
            e1.v = *(const int4*)(esrc + 8);
            ushort_t* dst = Aout + (size_t)(m0 + rr2) * KE + 1024 + c0e;
            ast(dst, e0.u[0]); ast(dst + 4, e0.u[1]);
            ast(dst + 8, e1.u[0]); ast(dst + 12, e1.u[1]);
        }
        if (s + 1 < SS) groupbar(barp, (s + 1) * 32);
    }
}

// Fill A_dec ctx columns for all 19 steps (decoder h-init comes from ctx_f/ctx_b)
__global__ void fill_ctx(const ushort_t* __restrict__ ctx_b, ushort_t* __restrict__ A_dec) {
    int idx = blockIdx.x * 256 + threadIdx.x;  // 19*256*1024
    int t = idx >> 18;
    int r = idx & 262143;
    int b = r >> 10;
    int k = r & 1023;
    A_dec[((size_t)(t * BB + b)) * KE + 128 + k] = ctx_b[r];
}

// ---------------------------------------------------------------------------
// 128x128 MFMA GEMM, ping-pong LDS + lgkm-only barrier + XOR swizzle.
// ---------------------------------------------------------------------------
template <typename OutT>
__global__ __launch_bounds__(256) void gemm128(const ushort_t* __restrict__ A,
                                               const ushort_t* __restrict__ W,
                                               OutT* __restrict__ C,
                                               int K, int lda, int ldw, int ldc) {
    __shared__ ushort_t As[2][128 * 32];
    __shared__ ushort_t Bs[2][128 * 32];
    int tid = threadIdx.x;
    int lane = tid & 63, wave = tid >> 6;
    int m0 = blockIdx.y << 7, n0 = blockIdx.x << 7;
    int row0 = tid >> 2, kc0 = (tid & 3) << 3;
    const ushort_t* a0p = A + (size_t)(m0 + row0) * lda + kc0;
    const ushort_t* a1p = A + (size_t)(m0 + row0 + 64) * lda + kc0;
    const ushort_t* w0p = W + (size_t)(n0 + row0) * ldw + kc0;
    const ushort_t* w1p = W + (size_t)(n0 + row0 + 64) * ldw + kc0;
    int mq = (wave >> 1) << 6, nq = (wave & 1) << 6;
    int r16 = lane & 15, q8 = (lane >> 4) << 3;
    const int sx = ((row0 >> 1) & 3) << 3;
    const int sw0 = (row0 << 5) + (kc0 ^ sx);
    const int sw1 = ((row0 + 64) << 5) + (kc0 ^ sx);
    f32x4 zero4 = {0.f, 0.f, 0.f, 0.f};
    f32x4 acc[4][4];
#pragma unroll
    for (int i = 0; i < 4; ++i)
#pragma unroll
        for (int j = 0; j < 4; ++j) acc[i][j] = zero4;
    int4 va0 = *(const int4*)(a0p);
    int4 va1 = *(const int4*)(a1p);
    int4 vb0 = *(const int4*)(w0p);
    int4 vb1 = *(const int4*)(w1p);
    *(int4*)(As[0] + sw0) = va0;
    *(int4*)(As[0] + sw1) = va1;
    *(int4*)(Bs[0] + sw0) = vb0;
    *(int4*)(Bs[0] + sw1) = vb1;
    va0 = *(const int4*)(a0p + 32);
    va1 = *(const int4*)(a1p + 32);
    vb0 = *(const int4*)(w0p + 32);
    vb1 = *(const int4*)(w1p + 32);
    __syncthreads();
    int p = 0;
    for (int k0 = 0; k0 < K; k0 += 32) {
        int kn = k0 + 32;
        if (kn < K) {
            *(int4*)(As[p ^ 1] + sw0) = va0;
            *(int4*)(As[p ^ 1] + sw1) = va1;
            *(int4*)(Bs[p ^ 1] + sw0) = vb0;
            *(int4*)(Bs[p ^ 1] + sw1) = vb1;
            if (kn + 32 < K) {
                va0 = *(const int4*)(a0p + kn + 32);
                va1 = *(const int4*)(a1p + kn + 32);
                vb0 = *(const int4*)(w0p + kn + 32);
                vb1 = *(const int4*)(w1p + kn + 32);
            }
        }
        bf16x8 af[4], bfv[4];
#pragma unroll
        for (int i = 0; i < 4; ++i) {
            int ar = mq + i * 16 + r16;
            af[i] = *(const bf16x8*)(As[p] + (ar << 5) + (q8 ^ ((((ar) >> 1) & 3) << 3)));
        }
#pragma unroll
        for (int j = 0; j < 4; ++j) {
            int br = nq + j * 16 + r16;
            bfv[j] = *(const bf16x8*)(Bs[p] + (br << 5) + (q8 ^ ((((br) >> 1) & 3) << 3)));
        }
#pragma unroll
        for (int i = 0; i < 4; ++i)
#pragma unroll
            for (int j = 0; j < 4; ++j) acc[i][j] = MFMA16(af[i], bfv[j], acc[i][j]);
        LGKM_BARRIER();
        p ^= 1;
    }
    int rbase = (lane >> 4) << 2;
#pragma unroll
    for (int i = 0; i < 4; ++i)
#pragma unroll
        for (int j = 0; j < 4; ++j)
#pragma unroll
            for (int r = 0; r < 4; ++r)
                storeC(&C[(size_t)(m0 + mq + i * 16 + rbase + r) * ldc + (n0 + nq + j * 16 + r16)],
                       acc[i][j][r]);
}

// ---------------------------------------------------------------------------
// PERSISTENT decoder v2: same decomposition as enc_all; 3 gate groups (wave 3
// stages only); writes H_all[t] each step.
// ---------------------------------------------------------------------------
__global__ __launch_bounds__(256) void dec_all(
    const ushort_t* __restrict__ ctx_b, ushort_t* __restrict__ H_all,
    const ushort_t* __restrict__ W, const ushort_t* __restrict__ gi_all,
    const float* __restrict__ bi, const float* __restrict__ bh,
    const float* __restrict__ ctx_f, int* __restrict__ bar) {
    __shared__ __align__(16) ushort_t As[2][32 * 64];
    __shared__ float gbuf[3][32 * 33];
    int tid = threadIdx.x;
    int bid = blockIdx.x;
    int lane = tid & 63, g = tid >> 6;
    int jb = (bid & 7) * 4 + ((bid >> 3) & 3);
    int mg = bid >> 5;
    int j0 = jb << 5, m0 = mg << 5;
    int* barp = bar + 512 + mg * 64;
    int r16 = lane & 15, q = lane >> 4, q8 = q << 3;
    int srow = tid >> 3, skc = (tid & 7) << 3;
    const size_t offA = (size_t)(m0 + srow) * HH + skc;
    const int sx = (srow & 7) << 3;
    const int sw = (srow << 6) + (skc ^ sx);
    const ushort_t* wb0 = W + (size_t)(g * 1024 + j0 + r16) * HH + q8;
    const ushort_t* wb1 = wb0 + (size_t)16 * HH;
    int m = tid & 31, jc0 = (tid >> 5) << 2;
    int bgl = m0 + m, gjj = j0 + jc0;
    float bir[4], bhr[4], biz[4], bhz[4], bhn[4], bin[4];
#pragma unroll
    for (int u = 0; u < 4; ++u) {
        int jg = gjj + u;
        bir[u] = bi[jg];        bhr[u] = bh[jg];
        biz[u] = bi[1024 + jg]; bhz[u] = bh[1024 + jg];
        bhn[u] = bh[2048 + jg]; bin[u] = bi[2048 + jg];
    }
    float hreg[4];
#pragma unroll
    for (int u = 0; u < 4; ++u) hreg[u] = ctx_f[(size_t)bgl * HH + gjj + u];

#pragma unroll 1
    for (int t = 0; t < TT - 1; ++t) {
        const ushort_t* Ain = t ? (H_all + (size_t)(t - 1) * BB * HH) : ctx_b;
        ushort_t* Aout = H_all + (size_t)t * BB * HH;
        const ushort_t* ap = Ain + offA;
        f32x4 zero = {0.f, 0.f, 0.f, 0.f};
        f32x4 acc[2][2];
        acc[0][0] = zero; acc[0][1] = zero; acc[1][0] = zero; acc[1][1] = zero;
        u64_t t0a = ald(ap), t0b = ald(ap + 4);
        u64_t b0a = ald(ap + 64), b0b = ald(ap + 68);
        u64_t b1a = ald(ap + 128), b1b = ald(ap + 132);
        bf16x8 wf00 = {0, 0, 0, 0, 0, 0, 0, 0}, wf01 = wf00, wf10 = wf00, wf11 = wf00;
        if (g < 3) {
            wf00 = *(const bf16x8*)(wb0);
            wf01 = *(const bf16x8*)(wb1);
            wf10 = *(const bf16x8*)(wb0 + 32);
            wf11 = *(const bf16x8*)(wb1 + 32);
        }
        { union { u64_t u[2]; int4 v; } st; st.u[0] = t0a; st.u[1] = t0b;
          *(int4*)(As[0] + sw) = st.v; }
        __syncthreads();
        const int NC = HH / 64;  // 16
#pragma unroll
        for (int c = 0; c < NC; ++c) {
            int kn = (c + 1) << 6;
            bf16x8 wn00, wn01, wn10, wn11;
            if (c + 1 < NC) {
                union { u64_t u[2]; int4 v; } st;
                if (c & 1) { st.u[0] = b1a; st.u[1] = b1b; }
                else       { st.u[0] = b0a; st.u[1] = b0b; }
                *(int4*)(As[(c + 1) & 1] + sw) = st.v;
                if (c + 3 < NC) {
                    int kf = (c + 3) << 6;
                    if (c & 1) { b1a = ald(ap + kf); b1b = ald(ap + kf + 4); }
                    else       { b0a = ald(ap + kf); b0b = ald(ap + kf + 4); }
                }
                if (g < 3) {
                    wn00 = *(const bf16x8*)(wb0 + kn);
                    wn01 = *(const bf16x8*)(wb1 + kn);
                    wn10 = *(const bf16x8*)(wb0 + kn + 32);
                    wn11 = *(const bf16x8*)(wb1 + kn + 32);
                }
            }
            if (g < 3) {
                const ushort_t* Ab = As[c & 1];
#pragma unroll
                for (int i = 0; i < 2; ++i) {
                    int row = (i << 4) + r16;
                    int xr = (row & 7) << 3;
                    bf16x8 af0 = *(const bf16x8*)(Ab + (row << 6) + (q8 ^ xr));
                    bf16x8 af1 = *(const bf16x8*)(Ab + (row << 6) + ((q8 + 32) ^ xr));
                    acc[i][0] = MFMA16(af0, wf00, acc[i][0]);
                    acc[i][1] = MFMA16(af0, wf01, acc[i][1]);
                    acc[i][0] = MFMA16(af1, wf10, acc[i][0]);
                    acc[i][1] = MFMA16(af1, wf11, acc[i][1]);
                }
                if (c + 1 < NC) { wf00 = wn00; wf01 = wn01; wf10 = wn10; wf11 = wn11; }
            }
            LGKM_BARRIER();
        }
        if (g < 3) {
#pragma unroll
            for (int i = 0; i < 2; ++i)
#pragma unroll
                for (int j2 = 0; j2 < 2; ++j2)
#pragma unroll
                    for (int r = 0; r < 4; ++r)
                        gbuf[g][(i * 16 + q * 4 + r) * 33 + j2 * 16 + r16] = acc[i][j2][r];
        }
        __syncthreads();
        const ushort_t* gib = gi_all + ((size_t)t * BB + bgl) * G3;
        union { u64_t u; ushort_t s4[4]; } gr, gz, gn;
        gr.u = *(const u64_t*)(gib + gjj);
        gz.u = *(const u64_t*)(gib + 1024 + gjj);
        gn.u = *(const u64_t*)(gib + 2048 + gjj);
        const float* gp0 = &gbuf[0][m * 33 + jc0];
        const float* gp1 = &gbuf[1][m * 33 + jc0];
        const float* gp2 = &gbuf[2][m * 33 + jc0];
        union { ushort_t s4[4]; u64_t u; } hb;
#pragma unroll
        for (int u = 0; u < 4; ++u) {
            float rr = sigm(gp0[u] + bhr[u] + bf2f(gr.s4[u]) + bir[u]);
            float zz = sigm(gp1[u] + bhz[u] + bf2f(gz.s4[u]) + biz[u]);
            float hn = gp2[u] + bhn[u];
            float inn = bf2f(gn.s4[u]) + bin[u];
            float nn = tanhf(inn + rr * hn);
            float h2 = (1.f - zz) * nn + zz * hreg[u];
            hreg[u] = h2;
            hb.s4[u] = f2bf(h2);
        }
        ast(Aout + (size_t)bgl * 1024 + gjj, hb.u);
        if (t + 1 < TT - 1) groupbar(barp, (t + 1) * 32);
    }
}

// ---------------------------------------------------------------------------
// BATCHED fused logits GEMM + CE partials, XCD-chunked (each XCD owns 5
// m-tiles; W panel fetched once per XCD, reused 5x from L2).
// ---------------------------------------------------------------------------
__global__ __launch_bounds__(256) void logits_ce(
    const ushort_t* __restrict__ A, const ushort_t* __restrict__ Wf,
    const float* __restrict__ bfc, const int* __restrict__ targets,
    float* __restrict__ part_max, float* __restrict__ part_sum,
    float* __restrict__ xt) {
    int bid = blockIdx.x;
    int xcd = bid & 7;
    int slot = bid >> 3;
    int n_t = slot / 5;
    int m_t = xcd * 5 + (slot - n_t * 5);
    if (m_t >= (TT - 1) * BB / 128) return;
    __shared__ ushort_t As[2][128 * 32];
    __shared__ ushort_t Bs[2][128 * 32];
    __shared__ float wm[128][2], ws2[128][2];
    int tid = threadIdx.x;
    int lane = tid & 63, wave = tid >> 6;
    int m0 = m_t << 7, n0 = n_t << 7;
    int row0 = tid >> 2, kc0 = (tid & 3) << 3;
    const ushort_t* a0p = A + (size_t)(m0 + row0) * HH + kc0;
    const ushort_t* a1p = A + (size_t)(m0 + row0 + 64) * HH + kc0;
    const ushort_t* w0p = Wf + (size_t)(n0 + row0) * HH + kc0;
    const ushort_t* w1p = Wf + (size_t)(n0 + row0 + 64) * HH + kc0;
    int mq = (wave >> 1) << 6, nq = (wave & 1) << 6;
    int r16 = lane & 15, q = lane >> 4, q8 = q << 3;
    const int sx = ((row0 >> 1) & 3) << 3;
    const int sw0 = (row0 << 5) + (kc0 ^ sx);
    const int sw1 = ((row0 + 64) << 5) + (kc0 ^ sx);
    f32x4 zero4 = {0.f, 0.f, 0.f, 0.f};
    f32x4 acc[4][4];
#pragma unroll
    for (int i = 0; i < 4; ++i)
#pragma unroll
        for (int j = 0; j < 4; ++j) acc[i][j] = zero4;
    int4 va0 = *(const int4*)(a0p);
    int4 va1 = *(const int4*)(a1p);
    int4 vb0 = *(const int4*)(w0p);
    int4 vb1 = *(const int4*)(w1p);
    *(int4*)(As[0] + sw0) = va0;
    *(int4*)(As[0] + sw1) = va1;
    *(int4*)(Bs[0] + sw0) = vb0;
    *(int4*)(Bs[0] + sw1) = vb1;
    va0 = *(const int4*)(a0p + 32);
    va1 = *(const int4*)(a1p + 32);
    vb0 = *(const int4*)(w0p + 32);
    vb1 = *(const int4*)(w1p + 32);
    __syncthreads();
    int p = 0;
    for (int k0 = 0; k0 < HH; k0 += 32) {
        int kn = k0 + 32;
        if (kn < HH) {
            *(int4*)(As[p ^ 1] + sw0) = va0;
            *(int4*)(As[p ^ 1] + sw1) = va1;
            *(int4*)(Bs[p ^ 1] + sw0) = vb0;
            *(int4*)(Bs[p ^ 1] + sw1) = vb1;
            if (kn + 32 < HH) {
                va0 = *(const int4*)(a0p + kn + 32);
                va1 = *(const int4*)(a1p + kn + 32);
                vb0 = *(const int4*)(w0p + kn + 32);
                vb1 = *(const int4*)(w1p + kn + 32);
            }
        }
        bf16x8 af[4], bfv[4];
#pragma unroll
        for (int i = 0; i < 4; ++i) {
            int ar = mq + i * 16 + r16;
            af[i] = *(const bf16x8*)(As[p] + (ar << 5) + (q8 ^ ((((ar) >> 1) & 3) << 3)));
        }
#pragma unroll
        for (int j = 0; j < 4; ++j) {
            int br = nq + j * 16 + r16;
            bfv[j] = *(const bf16x8*)(Bs[p] + (br << 5) + (q8 ^ ((((br) >> 1) & 3) << 3)));
        }
#pragma unroll
        for (int i = 0; i < 4; ++i)
#pragma unroll
            for (int j = 0; j < 4; ++j) acc[i][j] = MFMA16(af[i], bfv[j], acc[i][j]);
        LGKM_BARRIER();
        p ^= 1;
    }
    float bias[4];
#pragma unroll
    for (int j2 = 0; j2 < 4; ++j2) bias[j2] = bfc[n0 + nq + j2 * 16 + r16];
    int nw = wave & 1;
#pragma unroll
    for (int i = 0; i < 4; ++i) {
#pragma unroll
        for (int r = 0; r < 4; ++r) {
            int rloc = mq + i * 16 + q * 4 + r;
            int brow = m0 + rloc;
            int y = targets[(brow & 255) * TT + (brow >> 8) + 1];
            float v[4];
            float mx = -3.0e38f;
#pragma unroll
            for (int j2 = 0; j2 < 4; ++j2) {
                v[j2] = acc[i][j2][r] + bias[j2];
                if (n0 + nq + j2 * 16 + r16 == y) xt[brow] = v[j2];
                mx = fmaxf(mx, v[j2]);
            }
#pragma unroll
            for (int d = 1; d < 16; d <<= 1) mx = fmaxf(mx, __shfl_xor(mx, d, 64));
            float se = 0.f;
#pragma unroll
            for (int j2 = 0; j2 < 4; ++j2) se += expf(v[j2] - mx);
#pragma unroll
            for (int d = 1; d < 16; d <<= 1) se += __shfl_xor(se, d, 64);
            if (r16 == 0) { wm[rloc][nw] = mx; ws2[rloc][nw] = se; }
        }
    }
    __syncthreads();
    if (tid < 128) {
        float m0v = wm[tid][0], m1v = wm[tid][1];
        float M = fmaxf(m0v, m1v);
        float S = ws2[tid][0] * expf(m0v - M) + ws2[tid][1] * expf(m1v - M);
        int brow = m0 + tid;
        part_max[(size_t)brow * 256 + n_t] = M;
        part_sum[(size_t)brow * 256 + n_t] = S;
    }
}

// Merge 250 per-row partials -> CE for all 4864 rows; atomicAdd ce_sum[t]
__global__ void ce_merge(const float* __restrict__ pm, const float* __restrict__ ps,
                         const float* __restrict__ xt, float* __restrict__ ce_sum) {
    int row = blockIdx.x * 4 + (threadIdx.x >> 6);
    int lane = threadIdx.x & 63;
    const float* pmr = pm + (size_t)row * 256;
    const float* psr = ps + (size_t)row * 256;
    float lm[4];
    int cnt = 0;
    float mx = -3.0e38f;
    for (int i = lane; i < 250; i += 64) { float v = pmr[i]; lm[cnt++] = v; mx = fmaxf(mx, v); }
    for (int d = 1; d < 64; d <<= 1) mx = fmaxf(mx, __shfl_xor(mx, d, 64));
    float s = 0.f;
    cnt = 0;
    for (int i = lane; i < 250; i += 64) { s += psr[i] * expf(lm[cnt++] - mx); }
    for (int d = 1; d < 64; d <<= 1) s += __shfl_xor(s, d, 64);
    if (lane == 0) atomicAdd(&ce_sum[row >> 8], mx + logf(s) - xt[row]);
}

// loss = (1/T) * sum_t (ce_sum[t]/B) * (mask_sum[t]/B)
__global__ void finalize(const float* __restrict__ ce_sum, const int* __restrict__ targets,
                         float* __restrict__ out) {
    int lane = threadIdx.x;
    float term = 0.f;
    if (lane < TT - 1) {
        int msum = 0;
        for (int b = 0; b < BB; ++b) msum += (targets[b * TT + lane + 1] >= 1) ? 1 : 0;
        term = (ce_sum[lane] * (1.f / BB)) * ((float)msum * (1.f / BB));
    }
    for (int off = 32; off > 0; off >>= 1) term += __shfl_down(term, off, 64);
    if (lane == 0) out[0] = term * (1.f / TT);
}

extern "C" void kernel_launch(void* const* d_in, const int* in_sizes, int n_in,
                              void* d_out, int out_size, void* d_ws, size_t ws_size,
                              hipStream_t stream) {
    const int* inputs = (const int*)d_in[0];
    const int* targets = (const int*)d_in[1];
    const int* lengths = (const int*)d_in[2];
    const float* h0 = (const float*)d_in[3];
    const float* E_enc = (const float*)d_in[4];
    const float* E_dec = (const float*)d_in[5];
    const float* W_ih_e = (const float*)d_in[6];
    const float* W_hh_e = (const float*)d_in[7];
    const float* b_ih_e = (const float*)d_in[8];
    const float* b_hh_e = (const float*)d_in[9];
    const float* W_ih_d = (const float*)d_in[10];
    const float* W_hh_d = (const float*)d_in[11];
    const float* b_ih_d = (const float*)d_in[12];
    const float* b_hh_d = (const float*)d_in[13];
    const float* W_fc = (const float*)d_in[14];
    const float* b_fc = (const float*)d_in[15];

    char* ws = (char*)d_ws;
    size_t off = 0;
    auto alloc = [&](size_t bytes) -> char* {
        char* p = ws + off;
        off += (bytes + 255) & ~(size_t)255;
        return p;
    };
    const int MROWS = (TT - 1) * BB;  // 4864
    ushort_t* W_enc_big = (ushort_t*)alloc((size_t)G4 * KE * 2);
    ushort_t* W_dec_pad = (ushort_t*)alloc((size_t)G3 * KE * 2);
    ushort_t* W_hhd_b = (ushort_t*)alloc((size_t)G3 * HH * 2);
    ushort_t* W_fc_b = (ushort_t*)alloc((size_t)VV * HH * 2);
    ushort_t* emb_pad = (ushort_t*)alloc((size_t)SS * BB * 128 * 2);
    ushort_t* A_enc0 = (ushort_t*)alloc((size_t)BB * KE * 2);
    ushort_t* A_enc1 = (ushort_t*)alloc((size_t)BB * KE * 2);
    ushort_t* A_dec = (ushort_t*)alloc((size_t)MROWS * KE * 2);
    ushort_t* gi_dec = (ushort_t*)alloc((size_t)MROWS * G3 * 2);
    ushort_t* H_all = (ushort_t*)alloc((size_t)MROWS * HH * 2);
    float* ctx_f = (float*)alloc((size_t)BB * HH * 4);
    ushort_t* ctx_b = (ushort_t*)alloc((size_t)BB * HH * 2);
    float* part_max = (float*)alloc((size_t)MROWS * 256 * 4);
    float* part_sum = (float*)alloc((size_t)MROWS * 256 * 4);
    float* xt = (float*)alloc((size_t)MROWS * 4);
    float* ce_sum = (float*)alloc(64 * 4);
    int* bar = (int*)alloc(1024 * 4);

    // ---- prep ----
    prep_w<<<(G4 + G3) * (KE / 8) / 256, 256, 0, stream>>>(W_hh_e, W_ih_e, W_ih_d,
                                                           W_enc_big, W_dec_pad);
    conv_w<<<(G3 * HH + VV * HH) / 8 / 256, 256, 0, stream>>>(W_hh_d, W_fc, W_hhd_b, W_fc_b);
    {
        int nx = SS * BB * 128 + BB * KE + (TT - 1) * BB * 128 + 32 + 1024;
        prep_x<<<(nx + 255) / 256, 256, 0, stream>>>(inputs, targets, h0, E_enc, E_dec,
                                                     emb_pad, A_enc0, A_dec, ce_sum, bar);
    }

    // ---- encoder: ONE persistent launch, 256 blocks, per-m-group barriers ----
    enc_all<<<256, 256, 0, stream>>>(A_enc0, A_enc1, W_enc_big, b_ih_e, b_hh_e,
                                     h0, emb_pad, lengths, ctx_f, ctx_b, bar);

    // ---- decoder input-side gates: one big GEMM ----
    fill_ctx<<<((TT - 1) * BB * HH) / 256, 256, 0, stream>>>(ctx_b, A_dec);
    gemm128<ushort_t><<<dim3(G3 / 128, MROWS / 128), 256, 0, stream>>>(
        A_dec, W_dec_pad, gi_dec, KE, KE, KE, G3);

    // ---- decoder: ONE persistent launch, 19 steps writing H_all ----
    dec_all<<<256, 256, 0, stream>>>(ctx_b, H_all, W_hhd_b, gi_dec,
                                     b_ih_d, b_hh_d, ctx_f, bar);

    // ---- ONE batched logits+CE over all 19 steps (XCD-chunked), one merge ----
    logits_ce<<<10000, 256, 0, stream>>>(H_all, W_fc_b, b_fc, targets,
                                         part_max, part_sum, xt);
    ce_merge<<<MROWS / 4, 256, 0, stream>>>(part_max, part_sum, xt, ce_sum);

    finalize<<<1, 64, 0, stream>>>(ce_sum, targets, (float*)d_out);
}